// Round 4
// baseline (1375.687 us; speedup 1.0000x reference)
//
#include <hip/hip_runtime.h>

#define N_USERS 100000
#define M_ITEMS 50000
#define N_TOTAL (N_USERS + M_ITEMS)
#define D 64
#define NNZ 4000000
#define BATCH 4096

#define RPB 128                                   // rows per bucket (pow2)
#define BSHIFT 7
#define NBUCKETS ((N_TOTAL + RPB - 1) / RPB)      // 1172
#define BCAP 7680                                 // LDS edge capacity per bucket

// ---------------- init ----------------

__global__ void init_emb_kernel(const float4* __restrict__ ue,
                                const float4* __restrict__ ie,
                                float4* __restrict__ emb) {
    size_t i = (size_t)blockIdx.x * blockDim.x + threadIdx.x;
    const size_t nu4  = (size_t)N_USERS * D / 4;
    const size_t tot4 = (size_t)N_TOTAL * D / 4;
    if (i >= tot4) return;
    emb[i] = (i < nu4) ? ue[i] : ie[i - nu4];
}

__global__ void init_acc_kernel(const int* __restrict__ users,
                                const int* __restrict__ items,
                                const float* __restrict__ ue,
                                const float* __restrict__ ie,
                                float* __restrict__ u_acc,
                                float* __restrict__ i_acc) {
    int gid = blockIdx.x * blockDim.x + threadIdx.x;  // 2*BATCH*D threads
    int d = gid & (D - 1);
    int b = gid >> 6;
    if (b < BATCH) {
        u_acc[(size_t)b * D + d] = ue[(size_t)users[b] * D + d];
    } else if (b < 2 * BATCH) {
        int bb = b - BATCH;
        i_acc[(size_t)bb * D + d] = ie[(size_t)items[bb] * D + d];
    }
}

// ---------------- CSR build: two-level bucketing ----------------

// Pass 1: per-block LDS histogram of bucket ids, flushed with global atomics.
__global__ void bucket_hist_kernel(const int* __restrict__ rows,
                                   int* __restrict__ bucketcnt) {
    __shared__ int h[NBUCKETS];
    for (int i = threadIdx.x; i < NBUCKETS; i += blockDim.x) h[i] = 0;
    __syncthreads();
    int stride = gridDim.x * blockDim.x;
    for (int e = blockIdx.x * blockDim.x + threadIdx.x; e < NNZ; e += stride)
        atomicAdd(&h[rows[e] >> BSHIFT], 1);
    __syncthreads();
    for (int i = threadIdx.x; i < NBUCKETS; i += blockDim.x)
        if (h[i]) atomicAdd(&bucketcnt[i], h[i]);
}

// Pass 2: single-block exclusive scan over 1172 bucket counts (2 elems/thread).
__global__ void bucket_scan_kernel(const int* __restrict__ cnt,
                                   int* __restrict__ bucketoff,
                                   int* __restrict__ cursor) {
    __shared__ int sc[1024];
    int t = threadIdx.x;
    int i0 = t * 2, i1 = t * 2 + 1;
    int a = (i0 < NBUCKETS) ? cnt[i0] : 0;
    int b = (i1 < NBUCKETS) ? cnt[i1] : 0;
    sc[t] = a + b;
    __syncthreads();
    for (int o = 1; o < 1024; o <<= 1) {
        int v = (t >= o) ? sc[t - o] : 0;
        __syncthreads();
        sc[t] += v;
        __syncthreads();
    }
    int excl = (t == 0) ? 0 : sc[t - 1];
    if (i0 < NBUCKETS) { bucketoff[i0] = excl;     cursor[i0] = excl; }
    if (i1 < NBUCKETS) { bucketoff[i1] = excl + a; cursor[i1] = excl + a; }
    if (t == 0) bucketoff[NBUCKETS] = NNZ;
}

// Pass 3: scatter edges into bucket order. Writes are dense at each bucket's
// cursor front (1172 hot lines ~ 75 KB -> full lines reach HBM).
// Packed: x = (rowlocal<<18) | col  (col < 150000 < 2^18), y = bitcast(val).
__global__ void bucket_scatter_kernel(const int* __restrict__ rows,
                                      const int* __restrict__ cols,
                                      const float* __restrict__ vals,
                                      int* __restrict__ cursor,
                                      int2* __restrict__ bucketed) {
    int e = blockIdx.x * blockDim.x + threadIdx.x;
    if (e >= NNZ) return;
    int r = rows[e];
    int pos = atomicAdd(&cursor[r >> BSHIFT], 1);
    bucketed[pos] = make_int2(((r & (RPB - 1)) << 18) | cols[e],
                              __float_as_int(vals[e]));
}

// Pass 4: per-bucket counting sort in LDS -> exact CSR segment + row_start.
__global__ void local_sort_kernel(const int* __restrict__ bucketoff,
                                  const int2* __restrict__ bucketed,
                                  int* __restrict__ row_start,
                                  int2* __restrict__ edges) {
    __shared__ int hist[RPB];
    __shared__ int sc[RPB];
    __shared__ int lcur[RPB];
    __shared__ int2 buf[BCAP];
    int b = blockIdx.x;
    int t = threadIdx.x;
    int s = bucketoff[b], e = bucketoff[b + 1], n = e - s;

    if (t < RPB) hist[t] = 0;
    __syncthreads();
    for (int i = t; i < n; i += 256) {
        int2 ev = bucketed[s + i];
        atomicAdd(&hist[(unsigned)ev.x >> 18], 1);
    }
    __syncthreads();
    if (t < RPB) sc[t] = hist[t];
    __syncthreads();
    for (int o = 1; o < RPB; o <<= 1) {
        int v = (t < RPB && t >= o) ? sc[t - o] : 0;
        __syncthreads();
        if (t < RPB) sc[t] += v;
        __syncthreads();
    }
    if (t < RPB) {
        int excl = (t == 0) ? 0 : sc[t - 1];
        lcur[t] = excl;
        int gr = b * RPB + t;
        if (gr < N_TOTAL) row_start[gr] = s + excl;
    }
    if (b == 0 && t == 0) row_start[N_TOTAL] = NNZ;
    __syncthreads();
    for (int i = t; i < n; i += 256) {
        int2 ev = bucketed[s + i];
        int rl = (unsigned)ev.x >> 18;
        int c  = ev.x & 0x3FFFF;
        int p = atomicAdd(&lcur[rl], 1);
        int2 outv = make_int2(c, ev.y);
        if (p < BCAP) buf[p] = outv;
        else          edges[s + p] = outv;   // statistically-impossible overflow path
    }
    __syncthreads();
    int m = (n < BCAP) ? n : BCAP;
    for (int i = t; i < m; i += 256) edges[s + i] = buf[i];
}

// ---------------- CSR SpMM: one wave per row, lane = dim ----------------

__global__ void spmm_csr_kernel(const int* __restrict__ row_start,
                                const int2* __restrict__ edges,
                                const float* __restrict__ emb_in,
                                float* __restrict__ emb_out) {
    int wave = (blockIdx.x * blockDim.x + threadIdx.x) >> 6;
    int lane = threadIdx.x & 63;
    if (wave >= N_TOTAL) return;
    int s = row_start[wave];
    int e = row_start[wave + 1];
    float acc = 0.0f;
    for (int base = s; base < e; base += 64) {
        int n = e - base; if (n > 64) n = 64;
        int c = 0; float v = 0.0f;
        if (base + lane < e) {
            int2 ev = edges[base + lane];
            c = ev.x;
            v = __int_as_float(ev.y);
        }
        for (int j = 0; j < n; ++j) {
            int   cj = __shfl(c, j, 64);
            float vj = __shfl(v, j, 64);
            acc += vj * emb_in[(size_t)cj * D + lane];
        }
    }
    emb_out[(size_t)wave * D + lane] = acc;
}

// Layer-3: segment sums ONLY for the 8192 batch rows, added into accs.
__global__ void layer3_kernel(const int* __restrict__ users,
                              const int* __restrict__ items,
                              const int* __restrict__ row_start,
                              const int2* __restrict__ edges,
                              const float* __restrict__ emb_in,
                              float* __restrict__ u_acc,
                              float* __restrict__ i_acc) {
    int wave = (blockIdx.x * blockDim.x + threadIdx.x) >> 6;
    int lane = threadIdx.x & 63;
    if (wave >= 2 * BATCH) return;
    int row;
    float* dst;
    if (wave < BATCH) {
        row = users[wave];
        dst = &u_acc[(size_t)wave * D];
    } else {
        int bb = wave - BATCH;
        row = N_USERS + items[bb];
        dst = &i_acc[(size_t)bb * D];
    }
    int s = row_start[row];
    int e = row_start[row + 1];
    float acc = 0.0f;
    for (int base = s; base < e; base += 64) {
        int n = e - base; if (n > 64) n = 64;
        int c = 0; float v = 0.0f;
        if (base + lane < e) {
            int2 ev = edges[base + lane];
            c = ev.x;
            v = __int_as_float(ev.y);
        }
        for (int j = 0; j < n; ++j) {
            int   cj = __shfl(c, j, 64);
            float vj = __shfl(v, j, 64);
            acc += vj * emb_in[(size_t)cj * D + lane];
        }
    }
    dst[lane] += acc;
}

__global__ void gather_acc_kernel(const int* __restrict__ users,
                                  const int* __restrict__ items,
                                  const float* __restrict__ emb,
                                  float* __restrict__ u_acc,
                                  float* __restrict__ i_acc) {
    int gid = blockIdx.x * blockDim.x + threadIdx.x;  // 2*BATCH*D threads
    int d = gid & (D - 1);
    int b = gid >> 6;
    if (b < BATCH) {
        u_acc[(size_t)b * D + d] += emb[(size_t)users[b] * D + d];
    } else if (b < 2 * BATCH) {
        int bb = b - BATCH;
        i_acc[(size_t)bb * D + d] += emb[((size_t)(N_USERS + items[bb])) * D + d];
    }
}

__global__ void final_dot_kernel(const float* __restrict__ u_acc,
                                 const float* __restrict__ i_acc,
                                 float* __restrict__ out) {
    int gid = blockIdx.x * blockDim.x + threadIdx.x;
    int b = gid >> 6;
    int lane = gid & 63;
    if (b >= BATCH) return;
    float p = u_acc[(size_t)b * D + lane] * i_acc[(size_t)b * D + lane];
#pragma unroll
    for (int o = 32; o; o >>= 1) p += __shfl_xor(p, o, 64);
    if (lane == 0) out[b] = p * (1.0f / 16.0f);
}

// ---------------- launch ----------------

extern "C" void kernel_launch(void* const* d_in, const int* in_sizes, int n_in,
                              void* d_out, int out_size, void* d_ws, size_t ws_size,
                              hipStream_t stream) {
    const int*   users = (const int*)d_in[0];
    const int*   items = (const int*)d_in[1];
    const float* ue    = (const float*)d_in[2];
    const float* ie    = (const float*)d_in[3];
    const int*   rows  = (const int*)d_in[4];
    const int*   cols  = (const int*)d_in[5];
    const float* vals  = (const float*)d_in[6];
    float*       out   = (float*)d_out;

    char* ws = (char*)d_ws;
    size_t off = 0;
    auto alloc = [&](size_t bytes) {
        void* p = ws + off;
        off += (bytes + 255) & ~(size_t)255;
        return p;
    };
    const size_t NB = (size_t)N_TOTAL * D * sizeof(float);   // 38.4 MB
    float* embA      = (float*)alloc(NB);
    float* embB      = (float*)alloc(NB);
    float* u_acc     = (float*)alloc((size_t)BATCH * D * sizeof(float));
    float* i_acc     = (float*)alloc((size_t)BATCH * D * sizeof(float));
    int*   row_start = (int*)alloc(((size_t)N_TOTAL + 1) * sizeof(int));
    int*   bucketcnt = (int*)alloc((size_t)NBUCKETS * sizeof(int));
    int*   bucketoff = (int*)alloc(((size_t)NBUCKETS + 1) * sizeof(int));
    int*   cursor    = (int*)alloc((size_t)NBUCKETS * sizeof(int));
    int2*  edges     = (int2*)alloc((size_t)NNZ * sizeof(int2));
    // bucketed scratch aliases embB: only live before layer-1 SpMM writes embB.
    int2*  bucketed  = (int2*)embB;

    // init
    {
        size_t tot4 = (size_t)N_TOTAL * D / 4;
        init_emb_kernel<<<(unsigned)((tot4 + 255) / 256), 256, 0, stream>>>(
            (const float4*)ue, (const float4*)ie, (float4*)embA);
        init_acc_kernel<<<(2 * BATCH * D + 255) / 256, 256, 0, stream>>>(
            users, items, ue, ie, u_acc, i_acc);
    }

    // CSR build (two-level bucketing)
    hipMemsetAsync(bucketcnt, 0, (size_t)NBUCKETS * sizeof(int), stream);
    bucket_hist_kernel<<<512, 256, 0, stream>>>(rows, bucketcnt);
    bucket_scan_kernel<<<1, 1024, 0, stream>>>(bucketcnt, bucketoff, cursor);
    bucket_scatter_kernel<<<(NNZ + 255) / 256, 256, 0, stream>>>(
        rows, cols, vals, cursor, bucketed);
    local_sort_kernel<<<NBUCKETS, 256, 0, stream>>>(
        bucketoff, bucketed, row_start, edges);

    // Layer 1: embA -> embB
    spmm_csr_kernel<<<(N_TOTAL * 64 + 255) / 256, 256, 0, stream>>>(
        row_start, edges, embA, embB);
    gather_acc_kernel<<<(2 * BATCH * D + 255) / 256, 256, 0, stream>>>(
        users, items, embB, u_acc, i_acc);

    // Layer 2: embB -> embA
    spmm_csr_kernel<<<(N_TOTAL * 64 + 255) / 256, 256, 0, stream>>>(
        row_start, edges, embB, embA);
    gather_acc_kernel<<<(2 * BATCH * D + 255) / 256, 256, 0, stream>>>(
        users, items, embA, u_acc, i_acc);

    // Layer 3: only the 8192 batch rows, straight into accs
    layer3_kernel<<<(2 * BATCH * 64 + 255) / 256, 256, 0, stream>>>(
        users, items, row_start, edges, embA, u_acc, i_acc);

    final_dot_kernel<<<(BATCH * 64 + 255) / 256, 256, 0, stream>>>(u_acc, i_acc, out);
}

// Round 5
// 777.098 us; speedup vs baseline: 1.7703x; 1.7703x over previous
//
#include <hip/hip_runtime.h>

#define N_USERS 100000
#define M_ITEMS 50000
#define N_TOTAL (N_USERS + M_ITEMS)
#define D 64
#define NNZ 4000000
#define BATCH 4096

#define RPB 128                                   // rows per bucket (pow2)
#define BSHIFT 7
#define NBUCKETS ((N_TOTAL + RPB - 1) / RPB)      // 1172
#define BCAP 7680                                 // LDS edge capacity per bucket

#define TILE 16384                                // edges per scatter block
#define SCAT_BLOCKS ((NNZ + TILE - 1) / TILE)     // 245

// ---------------- init ----------------

__global__ void init_emb_kernel(const float4* __restrict__ ue,
                                const float4* __restrict__ ie,
                                float4* __restrict__ emb) {
    size_t i = (size_t)blockIdx.x * blockDim.x + threadIdx.x;
    const size_t nu4  = (size_t)N_USERS * D / 4;
    const size_t tot4 = (size_t)N_TOTAL * D / 4;
    if (i >= tot4) return;
    emb[i] = (i < nu4) ? ue[i] : ie[i - nu4];
}

__global__ void init_acc_kernel(const int* __restrict__ users,
                                const int* __restrict__ items,
                                const float* __restrict__ ue,
                                const float* __restrict__ ie,
                                float* __restrict__ u_acc,
                                float* __restrict__ i_acc) {
    int gid = blockIdx.x * blockDim.x + threadIdx.x;  // 2*BATCH*D threads
    int d = gid & (D - 1);
    int b = gid >> 6;
    if (b < BATCH) {
        u_acc[(size_t)b * D + d] = ue[(size_t)users[b] * D + d];
    } else if (b < 2 * BATCH) {
        int bb = b - BATCH;
        i_acc[(size_t)bb * D + d] = ie[(size_t)items[bb] * D + d];
    }
}

// ---------------- CSR build: two-level bucketing ----------------

// Pass 1: per-block LDS histogram of bucket ids, flushed with global atomics.
__global__ void bucket_hist_kernel(const int* __restrict__ rows,
                                   int* __restrict__ bucketcnt) {
    __shared__ int h[NBUCKETS];
    for (int i = threadIdx.x; i < NBUCKETS; i += blockDim.x) h[i] = 0;
    __syncthreads();
    int stride = gridDim.x * blockDim.x;
    for (int e = blockIdx.x * blockDim.x + threadIdx.x; e < NNZ; e += stride)
        atomicAdd(&h[rows[e] >> BSHIFT], 1);
    __syncthreads();
    for (int i = threadIdx.x; i < NBUCKETS; i += blockDim.x)
        if (h[i]) atomicAdd(&bucketcnt[i], h[i]);
}

// Pass 2: single-block exclusive scan over 1172 bucket counts (2 elems/thread).
__global__ void bucket_scan_kernel(const int* __restrict__ cnt,
                                   int* __restrict__ bucketoff,
                                   int* __restrict__ cursor) {
    __shared__ int sc[1024];
    int t = threadIdx.x;
    int i0 = t * 2, i1 = t * 2 + 1;
    int a = (i0 < NBUCKETS) ? cnt[i0] : 0;
    int b = (i1 < NBUCKETS) ? cnt[i1] : 0;
    sc[t] = a + b;
    __syncthreads();
    for (int o = 1; o < 1024; o <<= 1) {
        int v = (t >= o) ? sc[t - o] : 0;
        __syncthreads();
        sc[t] += v;
        __syncthreads();
    }
    int excl = (t == 0) ? 0 : sc[t - 1];
    if (i0 < NBUCKETS) { bucketoff[i0] = excl;     cursor[i0] = excl; }
    if (i1 < NBUCKETS) { bucketoff[i1] = excl + a; cursor[i1] = excl + a; }
    if (t == 0) bucketoff[NBUCKETS] = NNZ;
}

// Pass 3 (tile-aggregated): each block reserves per-bucket ranges with ONE
// global atomic per touched bucket, then writes contiguous runs per bucket.
// Packed: x = (rowlocal<<18) | col  (col < 150000 < 2^18), y = bitcast(val).
__global__ void bucket_scatter_kernel(const int* __restrict__ rows,
                                      const int* __restrict__ cols,
                                      const float* __restrict__ vals,
                                      int* __restrict__ cursor,
                                      int2* __restrict__ bucketed) {
    __shared__ int hist[NBUCKETS];
    __shared__ int lbase[NBUCKETS];
    int t = threadIdx.x;
    size_t start = (size_t)blockIdx.x * TILE;
    int n = (int)(((size_t)NNZ - start < TILE) ? ((size_t)NNZ - start) : TILE);

    for (int i = t; i < NBUCKETS; i += 256) hist[i] = 0;
    __syncthreads();
    // Phase A: local histogram
    for (int i = t; i < n; i += 256)
        atomicAdd(&hist[rows[start + i] >> BSHIFT], 1);
    __syncthreads();
    // Phase B: one global reservation per touched bucket
    for (int i = t; i < NBUCKETS; i += 256) {
        int c = hist[i];
        lbase[i] = c ? atomicAdd(&cursor[i], c) : 0;
        hist[i] = 0;  // reuse as local rank counter
    }
    __syncthreads();
    // Phase C: rank locally, write contiguous runs
    for (int i = t; i < n; i += 256) {
        int r = rows[start + i];
        int bkt = r >> BSHIFT;
        int p = lbase[bkt] + atomicAdd(&hist[bkt], 1);
        bucketed[p] = make_int2(((r & (RPB - 1)) << 18) | cols[start + i],
                                __float_as_int(vals[start + i]));
    }
}

// Pass 4: per-bucket counting sort in LDS -> exact CSR segment + row_start.
__global__ void local_sort_kernel(const int* __restrict__ bucketoff,
                                  const int2* __restrict__ bucketed,
                                  int* __restrict__ row_start,
                                  int2* __restrict__ edges) {
    __shared__ int hist[RPB];
    __shared__ int sc[RPB];
    __shared__ int lcur[RPB];
    __shared__ int2 buf[BCAP];
    int b = blockIdx.x;
    int t = threadIdx.x;
    int s = bucketoff[b], e = bucketoff[b + 1], n = e - s;

    if (t < RPB) hist[t] = 0;
    __syncthreads();
    for (int i = t; i < n; i += 256) {
        int2 ev = bucketed[s + i];
        atomicAdd(&hist[(unsigned)ev.x >> 18], 1);
    }
    __syncthreads();
    if (t < RPB) sc[t] = hist[t];
    __syncthreads();
    for (int o = 1; o < RPB; o <<= 1) {
        int v = (t < RPB && t >= o) ? sc[t - o] : 0;
        __syncthreads();
        if (t < RPB) sc[t] += v;
        __syncthreads();
    }
    if (t < RPB) {
        int excl = (t == 0) ? 0 : sc[t - 1];
        lcur[t] = excl;
        int gr = b * RPB + t;
        if (gr < N_TOTAL) row_start[gr] = s + excl;
    }
    if (b == 0 && t == 0) row_start[N_TOTAL] = NNZ;
    __syncthreads();
    for (int i = t; i < n; i += 256) {
        int2 ev = bucketed[s + i];
        int rl = (unsigned)ev.x >> 18;
        int c  = ev.x & 0x3FFFF;
        int p = atomicAdd(&lcur[rl], 1);
        int2 outv = make_int2(c, ev.y);
        if (p < BCAP) buf[p] = outv;
        else          edges[s + p] = outv;   // statistically-impossible overflow path
    }
    __syncthreads();
    int m = (n < BCAP) ? n : BCAP;
    for (int i = t; i < m; i += 256) edges[s + i] = buf[i];
}

// ---------------- CSR SpMM: one wave per row, lane = dim ----------------

__global__ void spmm_csr_kernel(const int* __restrict__ row_start,
                                const int2* __restrict__ edges,
                                const float* __restrict__ emb_in,
                                float* __restrict__ emb_out) {
    int wave = (blockIdx.x * blockDim.x + threadIdx.x) >> 6;
    int lane = threadIdx.x & 63;
    if (wave >= N_TOTAL) return;
    int s = row_start[wave];
    int e = row_start[wave + 1];
    float acc = 0.0f;
    for (int base = s; base < e; base += 64) {
        int n = e - base; if (n > 64) n = 64;
        int c = 0; float v = 0.0f;
        if (base + lane < e) {
            int2 ev = edges[base + lane];
            c = ev.x;
            v = __int_as_float(ev.y);
        }
        for (int j = 0; j < n; ++j) {
            int   cj = __shfl(c, j, 64);
            float vj = __shfl(v, j, 64);
            acc += vj * emb_in[(size_t)cj * D + lane];
        }
    }
    emb_out[(size_t)wave * D + lane] = acc;
}

// Layer-3: segment sums ONLY for the 8192 batch rows, added into accs.
__global__ void layer3_kernel(const int* __restrict__ users,
                              const int* __restrict__ items,
                              const int* __restrict__ row_start,
                              const int2* __restrict__ edges,
                              const float* __restrict__ emb_in,
                              float* __restrict__ u_acc,
                              float* __restrict__ i_acc) {
    int wave = (blockIdx.x * blockDim.x + threadIdx.x) >> 6;
    int lane = threadIdx.x & 63;
    if (wave >= 2 * BATCH) return;
    int row;
    float* dst;
    if (wave < BATCH) {
        row = users[wave];
        dst = &u_acc[(size_t)wave * D];
    } else {
        int bb = wave - BATCH;
        row = N_USERS + items[bb];
        dst = &i_acc[(size_t)bb * D];
    }
    int s = row_start[row];
    int e = row_start[row + 1];
    float acc = 0.0f;
    for (int base = s; base < e; base += 64) {
        int n = e - base; if (n > 64) n = 64;
        int c = 0; float v = 0.0f;
        if (base + lane < e) {
            int2 ev = edges[base + lane];
            c = ev.x;
            v = __int_as_float(ev.y);
        }
        for (int j = 0; j < n; ++j) {
            int   cj = __shfl(c, j, 64);
            float vj = __shfl(v, j, 64);
            acc += vj * emb_in[(size_t)cj * D + lane];
        }
    }
    dst[lane] += acc;
}

__global__ void gather_acc_kernel(const int* __restrict__ users,
                                  const int* __restrict__ items,
                                  const float* __restrict__ emb,
                                  float* __restrict__ u_acc,
                                  float* __restrict__ i_acc) {
    int gid = blockIdx.x * blockDim.x + threadIdx.x;  // 2*BATCH*D threads
    int d = gid & (D - 1);
    int b = gid >> 6;
    if (b < BATCH) {
        u_acc[(size_t)b * D + d] += emb[(size_t)users[b] * D + d];
    } else if (b < 2 * BATCH) {
        int bb = b - BATCH;
        i_acc[(size_t)bb * D + d] += emb[((size_t)(N_USERS + items[bb])) * D + d];
    }
}

__global__ void final_dot_kernel(const float* __restrict__ u_acc,
                                 const float* __restrict__ i_acc,
                                 float* __restrict__ out) {
    int gid = blockIdx.x * blockDim.x + threadIdx.x;
    int b = gid >> 6;
    int lane = gid & 63;
    if (b >= BATCH) return;
    float p = u_acc[(size_t)b * D + lane] * i_acc[(size_t)b * D + lane];
#pragma unroll
    for (int o = 32; o; o >>= 1) p += __shfl_xor(p, o, 64);
    if (lane == 0) out[b] = p * (1.0f / 16.0f);
}

// ---------------- launch ----------------

extern "C" void kernel_launch(void* const* d_in, const int* in_sizes, int n_in,
                              void* d_out, int out_size, void* d_ws, size_t ws_size,
                              hipStream_t stream) {
    const int*   users = (const int*)d_in[0];
    const int*   items = (const int*)d_in[1];
    const float* ue    = (const float*)d_in[2];
    const float* ie    = (const float*)d_in[3];
    const int*   rows  = (const int*)d_in[4];
    const int*   cols  = (const int*)d_in[5];
    const float* vals  = (const float*)d_in[6];
    float*       out   = (float*)d_out;

    char* ws = (char*)d_ws;
    size_t off = 0;
    auto alloc = [&](size_t bytes) {
        void* p = ws + off;
        off += (bytes + 255) & ~(size_t)255;
        return p;
    };
    const size_t NB = (size_t)N_TOTAL * D * sizeof(float);   // 38.4 MB
    float* embA      = (float*)alloc(NB);
    float* embB      = (float*)alloc(NB);
    float* u_acc     = (float*)alloc((size_t)BATCH * D * sizeof(float));
    float* i_acc     = (float*)alloc((size_t)BATCH * D * sizeof(float));
    int*   row_start = (int*)alloc(((size_t)N_TOTAL + 1) * sizeof(int));
    int*   bucketcnt = (int*)alloc((size_t)NBUCKETS * sizeof(int));
    int*   bucketoff = (int*)alloc(((size_t)NBUCKETS + 1) * sizeof(int));
    int*   cursor    = (int*)alloc((size_t)NBUCKETS * sizeof(int));
    int2*  edges     = (int2*)alloc((size_t)NNZ * sizeof(int2));
    // bucketed scratch aliases embB: only live before layer-1 SpMM writes embB.
    int2*  bucketed  = (int2*)embB;

    // init
    {
        size_t tot4 = (size_t)N_TOTAL * D / 4;
        init_emb_kernel<<<(unsigned)((tot4 + 255) / 256), 256, 0, stream>>>(
            (const float4*)ue, (const float4*)ie, (float4*)embA);
        init_acc_kernel<<<(2 * BATCH * D + 255) / 256, 256, 0, stream>>>(
            users, items, ue, ie, u_acc, i_acc);
    }

    // CSR build (two-level bucketing, tile-aggregated scatter)
    hipMemsetAsync(bucketcnt, 0, (size_t)NBUCKETS * sizeof(int), stream);
    bucket_hist_kernel<<<512, 256, 0, stream>>>(rows, bucketcnt);
    bucket_scan_kernel<<<1, 1024, 0, stream>>>(bucketcnt, bucketoff, cursor);
    bucket_scatter_kernel<<<SCAT_BLOCKS, 256, 0, stream>>>(
        rows, cols, vals, cursor, bucketed);
    local_sort_kernel<<<NBUCKETS, 256, 0, stream>>>(
        bucketoff, bucketed, row_start, edges);

    // Layer 1: embA -> embB
    spmm_csr_kernel<<<(N_TOTAL * 64 + 255) / 256, 256, 0, stream>>>(
        row_start, edges, embA, embB);
    gather_acc_kernel<<<(2 * BATCH * D + 255) / 256, 256, 0, stream>>>(
        users, items, embB, u_acc, i_acc);

    // Layer 2: embB -> embA
    spmm_csr_kernel<<<(N_TOTAL * 64 + 255) / 256, 256, 0, stream>>>(
        row_start, edges, embB, embA);
    gather_acc_kernel<<<(2 * BATCH * D + 255) / 256, 256, 0, stream>>>(
        users, items, embA, u_acc, i_acc);

    // Layer 3: only the 8192 batch rows, straight into accs
    layer3_kernel<<<(2 * BATCH * 64 + 255) / 256, 256, 0, stream>>>(
        users, items, row_start, edges, embA, u_acc, i_acc);

    final_dot_kernel<<<(BATCH * 64 + 255) / 256, 256, 0, stream>>>(u_acc, i_acc, out);
}

// Round 6
// 576.066 us; speedup vs baseline: 2.3881x; 1.3490x over previous
//
#include <hip/hip_runtime.h>

#define N_USERS 100000
#define M_ITEMS 50000
#define N_TOTAL (N_USERS + M_ITEMS)
#define D 64
#define NNZ 4000000
#define BATCH 4096

#define RPB 128                                   // rows per bucket (pow2)
#define BSHIFT 7
#define NBUCKETS ((N_TOTAL + RPB - 1) / RPB)      // 1172
#define BCAP 7680                                 // LDS edge capacity per bucket

#define TILE 16384                                // edges per scatter block
#define SCAT_BLOCKS ((NNZ + TILE - 1) / TILE)     // 245

// ---- bf16 helpers (RNE) ----
__device__ __forceinline__ unsigned pack_bf16(float a, float b) {
    unsigned ua = __float_as_uint(a);
    unsigned ub = __float_as_uint(b);
    ua = (ua + 0x7FFFu + ((ua >> 16) & 1u)) >> 16;
    ub = (ub + 0x7FFFu + ((ub >> 16) & 1u)) & 0xFFFF0000u;
    return ua | ub;
}
__device__ __forceinline__ float bf16_lo(unsigned p) { return __uint_as_float(p << 16); }
__device__ __forceinline__ float bf16_hi(unsigned p) { return __uint_as_float(p & 0xFFFF0000u); }

// ---------------- init ----------------

// Concatenate + convert fp32 embeddings to packed bf16 (2 dims per uint).
__global__ void init_emb_kernel(const float4* __restrict__ ue,
                                const float4* __restrict__ ie,
                                uint2* __restrict__ emb) {
    size_t i = (size_t)blockIdx.x * blockDim.x + threadIdx.x;  // one float4 -> uint2
    const size_t nu4  = (size_t)N_USERS * D / 4;
    const size_t tot4 = (size_t)N_TOTAL * D / 4;
    if (i >= tot4) return;
    float4 f = (i < nu4) ? ue[i] : ie[i - nu4];
    emb[i] = make_uint2(pack_bf16(f.x, f.y), pack_bf16(f.z, f.w));
}

__global__ void init_acc_kernel(const int* __restrict__ users,
                                const int* __restrict__ items,
                                const float* __restrict__ ue,
                                const float* __restrict__ ie,
                                float* __restrict__ u_acc,
                                float* __restrict__ i_acc) {
    int gid = blockIdx.x * blockDim.x + threadIdx.x;  // 2*BATCH*D threads
    int d = gid & (D - 1);
    int b = gid >> 6;
    if (b < BATCH) {
        u_acc[(size_t)b * D + d] = ue[(size_t)users[b] * D + d];
    } else if (b < 2 * BATCH) {
        int bb = b - BATCH;
        i_acc[(size_t)bb * D + d] = ie[(size_t)items[bb] * D + d];
    }
}

// ---------------- CSR build: two-level bucketing ----------------

__global__ void bucket_hist_kernel(const int* __restrict__ rows,
                                   int* __restrict__ bucketcnt) {
    __shared__ int h[NBUCKETS];
    for (int i = threadIdx.x; i < NBUCKETS; i += blockDim.x) h[i] = 0;
    __syncthreads();
    int stride = gridDim.x * blockDim.x;
    for (int e = blockIdx.x * blockDim.x + threadIdx.x; e < NNZ; e += stride)
        atomicAdd(&h[rows[e] >> BSHIFT], 1);
    __syncthreads();
    for (int i = threadIdx.x; i < NBUCKETS; i += blockDim.x)
        if (h[i]) atomicAdd(&bucketcnt[i], h[i]);
}

__global__ void bucket_scan_kernel(const int* __restrict__ cnt,
                                   int* __restrict__ bucketoff,
                                   int* __restrict__ cursor) {
    __shared__ int sc[1024];
    int t = threadIdx.x;
    int i0 = t * 2, i1 = t * 2 + 1;
    int a = (i0 < NBUCKETS) ? cnt[i0] : 0;
    int b = (i1 < NBUCKETS) ? cnt[i1] : 0;
    sc[t] = a + b;
    __syncthreads();
    for (int o = 1; o < 1024; o <<= 1) {
        int v = (t >= o) ? sc[t - o] : 0;
        __syncthreads();
        sc[t] += v;
        __syncthreads();
    }
    int excl = (t == 0) ? 0 : sc[t - 1];
    if (i0 < NBUCKETS) { bucketoff[i0] = excl;     cursor[i0] = excl; }
    if (i1 < NBUCKETS) { bucketoff[i1] = excl + a; cursor[i1] = excl + a; }
    if (t == 0) bucketoff[NBUCKETS] = NNZ;
}

// Tile-aggregated scatter: one global atomic per touched bucket per block.
__global__ void bucket_scatter_kernel(const int* __restrict__ rows,
                                      const int* __restrict__ cols,
                                      const float* __restrict__ vals,
                                      int* __restrict__ cursor,
                                      int2* __restrict__ bucketed) {
    __shared__ int hist[NBUCKETS];
    __shared__ int lbase[NBUCKETS];
    int t = threadIdx.x;
    size_t start = (size_t)blockIdx.x * TILE;
    int n = (int)(((size_t)NNZ - start < TILE) ? ((size_t)NNZ - start) : TILE);

    for (int i = t; i < NBUCKETS; i += 256) hist[i] = 0;
    __syncthreads();
    for (int i = t; i < n; i += 256)
        atomicAdd(&hist[rows[start + i] >> BSHIFT], 1);
    __syncthreads();
    for (int i = t; i < NBUCKETS; i += 256) {
        int c = hist[i];
        lbase[i] = c ? atomicAdd(&cursor[i], c) : 0;
        hist[i] = 0;  // reuse as local rank counter
    }
    __syncthreads();
    for (int i = t; i < n; i += 256) {
        int r = rows[start + i];
        int bkt = r >> BSHIFT;
        int p = lbase[bkt] + atomicAdd(&hist[bkt], 1);
        bucketed[p] = make_int2(((r & (RPB - 1)) << 18) | cols[start + i],
                                __float_as_int(vals[start + i]));
    }
}

// Per-bucket counting sort in LDS -> exact CSR segment + row_start.
__global__ void local_sort_kernel(const int* __restrict__ bucketoff,
                                  const int2* __restrict__ bucketed,
                                  int* __restrict__ row_start,
                                  int2* __restrict__ edges) {
    __shared__ int hist[RPB];
    __shared__ int sc[RPB];
    __shared__ int lcur[RPB];
    __shared__ int2 buf[BCAP];
    int b = blockIdx.x;
    int t = threadIdx.x;
    int s = bucketoff[b], e = bucketoff[b + 1], n = e - s;

    if (t < RPB) hist[t] = 0;
    __syncthreads();
    for (int i = t; i < n; i += 256) {
        int2 ev = bucketed[s + i];
        atomicAdd(&hist[(unsigned)ev.x >> 18], 1);
    }
    __syncthreads();
    if (t < RPB) sc[t] = hist[t];
    __syncthreads();
    for (int o = 1; o < RPB; o <<= 1) {
        int v = (t < RPB && t >= o) ? sc[t - o] : 0;
        __syncthreads();
        if (t < RPB) sc[t] += v;
        __syncthreads();
    }
    if (t < RPB) {
        int excl = (t == 0) ? 0 : sc[t - 1];
        lcur[t] = excl;
        int gr = b * RPB + t;
        if (gr < N_TOTAL) row_start[gr] = s + excl;
    }
    if (b == 0 && t == 0) row_start[N_TOTAL] = NNZ;
    __syncthreads();
    for (int i = t; i < n; i += 256) {
        int2 ev = bucketed[s + i];
        int rl = (unsigned)ev.x >> 18;
        int c  = ev.x & 0x3FFFF;
        int p = atomicAdd(&lcur[rl], 1);
        int2 outv = make_int2(c, ev.y);
        if (p < BCAP) buf[p] = outv;
        else          edges[s + p] = outv;
    }
    __syncthreads();
    int m = (n < BCAP) ? n : BCAP;
    for (int i = t; i < m; i += 256) edges[s + i] = buf[i];
}

// ---------------- bf16 CSR SpMM ----------------
// One wave per row. Lanes split: half = lane>>5 processes edges 2t+half;
// ui = lane&31 covers dims (2ui, 2ui+1) via one packed uint load (128 B/edge).
__global__ void spmm_csr_kernel(const int* __restrict__ row_start,
                                const int2* __restrict__ edges,
                                const unsigned* __restrict__ emb_in,   // bf16x2, 32 uints/row
                                unsigned* __restrict__ emb_out) {
    int wave = (blockIdx.x * blockDim.x + threadIdx.x) >> 6;
    int lane = threadIdx.x & 63;
    if (wave >= N_TOTAL) return;
    int half = lane >> 5;
    int ui   = lane & 31;
    int s = row_start[wave];
    int e = row_start[wave + 1];
    float acc0 = 0.0f, acc1 = 0.0f;
    for (int base = s; base < e; base += 64) {
        int n = e - base; if (n > 64) n = 64;
        int c = 0; float v = 0.0f;
        if (base + lane < e) {
            int2 ev = edges[base + lane];
            c = ev.x;
            v = __int_as_float(ev.y);
        }
        int tmax = (n + 1) >> 1;
        for (int t = 0; t < tmax; ++t) {
            int j = 2 * t + half;                 // < 64 always
            int   cj = __shfl(c, j, 64);
            float vj = __shfl(v, j, 64);
            float m  = (j < n) ? vj : 0.0f;
            unsigned p = emb_in[(size_t)cj * 32 + ui];
            acc0 += m * bf16_lo(p);
            acc1 += m * bf16_hi(p);
        }
    }
    acc0 += __shfl_xor(acc0, 32, 64);
    acc1 += __shfl_xor(acc1, 32, 64);
    if (half == 0)
        emb_out[(size_t)wave * 32 + ui] = pack_bf16(acc0, acc1);
}

// Layer-3: segment sums ONLY for the 8192 batch rows, added into fp32 accs.
__global__ void layer3_kernel(const int* __restrict__ users,
                              const int* __restrict__ items,
                              const int* __restrict__ row_start,
                              const int2* __restrict__ edges,
                              const unsigned* __restrict__ emb_in,  // bf16x2
                              float* __restrict__ u_acc,
                              float* __restrict__ i_acc) {
    int wave = (blockIdx.x * blockDim.x + threadIdx.x) >> 6;
    int lane = threadIdx.x & 63;
    if (wave >= 2 * BATCH) return;
    int half = lane >> 5;
    int ui   = lane & 31;
    int row;
    float* dst;
    if (wave < BATCH) {
        row = users[wave];
        dst = &u_acc[(size_t)wave * D];
    } else {
        int bb = wave - BATCH;
        row = N_USERS + items[bb];
        dst = &i_acc[(size_t)bb * D];
    }
    int s = row_start[row];
    int e = row_start[row + 1];
    float acc0 = 0.0f, acc1 = 0.0f;
    for (int base = s; base < e; base += 64) {
        int n = e - base; if (n > 64) n = 64;
        int c = 0; float v = 0.0f;
        if (base + lane < e) {
            int2 ev = edges[base + lane];
            c = ev.x;
            v = __int_as_float(ev.y);
        }
        int tmax = (n + 1) >> 1;
        for (int t = 0; t < tmax; ++t) {
            int j = 2 * t + half;
            int   cj = __shfl(c, j, 64);
            float vj = __shfl(v, j, 64);
            float m  = (j < n) ? vj : 0.0f;
            unsigned p = emb_in[(size_t)cj * 32 + ui];
            acc0 += m * bf16_lo(p);
            acc1 += m * bf16_hi(p);
        }
    }
    acc0 += __shfl_xor(acc0, 32, 64);
    acc1 += __shfl_xor(acc1, 32, 64);
    if (half == 0) {
        dst[2 * ui]     += acc0;
        dst[2 * ui + 1] += acc1;
    }
}

// After layers 1,2: pull bf16 emb rows at batch indices into fp32 accs.
__global__ void gather_acc_kernel(const int* __restrict__ users,
                                  const int* __restrict__ items,
                                  const unsigned* __restrict__ emb,  // bf16x2
                                  float* __restrict__ u_acc,
                                  float* __restrict__ i_acc) {
    int gid = blockIdx.x * blockDim.x + threadIdx.x;  // 2*BATCH*32 threads
    int ui = gid & 31;
    int b  = gid >> 5;
    if (b < BATCH) {
        unsigned p = emb[(size_t)users[b] * 32 + ui];
        u_acc[(size_t)b * D + 2 * ui]     += bf16_lo(p);
        u_acc[(size_t)b * D + 2 * ui + 1] += bf16_hi(p);
    } else if (b < 2 * BATCH) {
        int bb = b - BATCH;
        unsigned p = emb[((size_t)(N_USERS + items[bb])) * 32 + ui];
        i_acc[(size_t)bb * D + 2 * ui]     += bf16_lo(p);
        i_acc[(size_t)bb * D + 2 * ui + 1] += bf16_hi(p);
    }
}

__global__ void final_dot_kernel(const float* __restrict__ u_acc,
                                 const float* __restrict__ i_acc,
                                 float* __restrict__ out) {
    int gid = blockIdx.x * blockDim.x + threadIdx.x;
    int b = gid >> 6;
    int lane = gid & 63;
    if (b >= BATCH) return;
    float p = u_acc[(size_t)b * D + lane] * i_acc[(size_t)b * D + lane];
#pragma unroll
    for (int o = 32; o; o >>= 1) p += __shfl_xor(p, o, 64);
    if (lane == 0) out[b] = p * (1.0f / 16.0f);
}

// ---------------- launch ----------------

extern "C" void kernel_launch(void* const* d_in, const int* in_sizes, int n_in,
                              void* d_out, int out_size, void* d_ws, size_t ws_size,
                              hipStream_t stream) {
    const int*   users = (const int*)d_in[0];
    const int*   items = (const int*)d_in[1];
    const float* ue    = (const float*)d_in[2];
    const float* ie    = (const float*)d_in[3];
    const int*   rows  = (const int*)d_in[4];
    const int*   cols  = (const int*)d_in[5];
    const float* vals  = (const float*)d_in[6];
    float*       out   = (float*)d_out;

    char* ws = (char*)d_ws;
    size_t off = 0;
    auto alloc = [&](size_t bytes) {
        void* p = ws + off;
        off += (bytes + 255) & ~(size_t)255;
        return p;
    };
    const size_t NBH = (size_t)N_TOTAL * D * sizeof(unsigned short);  // 19.2 MB bf16
    unsigned* embA   = (unsigned*)alloc(NBH);
    unsigned* embB   = (unsigned*)alloc(NBH);
    float* u_acc     = (float*)alloc((size_t)BATCH * D * sizeof(float));
    float* i_acc     = (float*)alloc((size_t)BATCH * D * sizeof(float));
    int*   row_start = (int*)alloc(((size_t)N_TOTAL + 1) * sizeof(int));
    int*   bucketcnt = (int*)alloc((size_t)NBUCKETS * sizeof(int));
    int*   bucketoff = (int*)alloc(((size_t)NBUCKETS + 1) * sizeof(int));
    int*   cursor    = (int*)alloc((size_t)NBUCKETS * sizeof(int));
    int2*  edges     = (int2*)alloc((size_t)NNZ * sizeof(int2));
    int2*  bucketed  = (int2*)alloc((size_t)NNZ * sizeof(int2));

    // init
    {
        size_t tot4 = (size_t)N_TOTAL * D / 4;
        init_emb_kernel<<<(unsigned)((tot4 + 255) / 256), 256, 0, stream>>>(
            (const float4*)ue, (const float4*)ie, (uint2*)embA);
        init_acc_kernel<<<(2 * BATCH * D + 255) / 256, 256, 0, stream>>>(
            users, items, ue, ie, u_acc, i_acc);
    }

    // CSR build (two-level bucketing, tile-aggregated scatter)
    hipMemsetAsync(bucketcnt, 0, (size_t)NBUCKETS * sizeof(int), stream);
    bucket_hist_kernel<<<512, 256, 0, stream>>>(rows, bucketcnt);
    bucket_scan_kernel<<<1, 1024, 0, stream>>>(bucketcnt, bucketoff, cursor);
    bucket_scatter_kernel<<<SCAT_BLOCKS, 256, 0, stream>>>(
        rows, cols, vals, cursor, bucketed);
    local_sort_kernel<<<NBUCKETS, 256, 0, stream>>>(
        bucketoff, bucketed, row_start, edges);

    // Layer 1: embA -> embB
    spmm_csr_kernel<<<(N_TOTAL * 64 + 255) / 256, 256, 0, stream>>>(
        row_start, edges, embA, embB);
    gather_acc_kernel<<<(2 * BATCH * 32 + 255) / 256, 256, 0, stream>>>(
        users, items, embB, u_acc, i_acc);

    // Layer 2: embB -> embA
    spmm_csr_kernel<<<(N_TOTAL * 64 + 255) / 256, 256, 0, stream>>>(
        row_start, edges, embB, embA);
    gather_acc_kernel<<<(2 * BATCH * 32 + 255) / 256, 256, 0, stream>>>(
        users, items, embA, u_acc, i_acc);

    // Layer 3: only the 8192 batch rows, straight into accs
    layer3_kernel<<<(2 * BATCH * 64 + 255) / 256, 256, 0, stream>>>(
        users, items, row_start, edges, embA, u_acc, i_acc);

    final_dot_kernel<<<(BATCH * 64 + 255) / 256, 256, 0, stream>>>(u_acc, i_acc, out);
}

// Round 7
// 492.877 us; speedup vs baseline: 2.7911x; 1.1688x over previous
//
#include <hip/hip_runtime.h>

#define N_USERS 100000
#define M_ITEMS 50000
#define N_TOTAL (N_USERS + M_ITEMS)
#define D 64
#define NNZ 4000000
#define BATCH 4096

#define RPB 128                                   // rows per bucket (pow2)
#define BSHIFT 7
#define NBUCKETS ((N_TOTAL + RPB - 1) / RPB)      // 1172
#define BCAP 7680                                 // LDS edge capacity per bucket

#define TILE 16384                                // edges per scatter block
#define SCAT_BLOCKS ((NNZ + TILE - 1) / TILE)     // 245

// ---- bf16 helpers (RNE) ----
__device__ __forceinline__ unsigned pack_bf16(float a, float b) {
    unsigned ua = __float_as_uint(a);
    unsigned ub = __float_as_uint(b);
    ua = (ua + 0x7FFFu + ((ua >> 16) & 1u)) >> 16;
    ub = (ub + 0x7FFFu + ((ub >> 16) & 1u)) & 0xFFFF0000u;
    return ua | ub;
}
__device__ __forceinline__ float bf16_lo(unsigned p) { return __uint_as_float(p << 16); }
__device__ __forceinline__ float bf16_hi(unsigned p) { return __uint_as_float(p & 0xFFFF0000u); }

// ---------------- init ----------------

// Concatenate + convert fp32 embeddings to packed bf16 (2 dims per uint).
__global__ void init_emb_kernel(const float4* __restrict__ ue,
                                const float4* __restrict__ ie,
                                uint2* __restrict__ emb) {
    size_t i = (size_t)blockIdx.x * blockDim.x + threadIdx.x;  // one float4 -> uint2
    const size_t nu4  = (size_t)N_USERS * D / 4;
    const size_t tot4 = (size_t)N_TOTAL * D / 4;
    if (i >= tot4) return;
    float4 f = (i < nu4) ? ue[i] : ie[i - nu4];
    emb[i] = make_uint2(pack_bf16(f.x, f.y), pack_bf16(f.z, f.w));
}

__global__ void init_acc_kernel(const int* __restrict__ users,
                                const int* __restrict__ items,
                                const float* __restrict__ ue,
                                const float* __restrict__ ie,
                                float* __restrict__ u_acc,
                                float* __restrict__ i_acc) {
    int gid = blockIdx.x * blockDim.x + threadIdx.x;  // 2*BATCH*D threads
    int d = gid & (D - 1);
    int b = gid >> 6;
    if (b < BATCH) {
        u_acc[(size_t)b * D + d] = ue[(size_t)users[b] * D + d];
    } else if (b < 2 * BATCH) {
        int bb = b - BATCH;
        i_acc[(size_t)bb * D + d] = ie[(size_t)items[bb] * D + d];
    }
}

// ---------------- CSR build: two-level bucketing ----------------

__global__ void bucket_hist_kernel(const int* __restrict__ rows,
                                   int* __restrict__ bucketcnt) {
    __shared__ int h[NBUCKETS];
    for (int i = threadIdx.x; i < NBUCKETS; i += blockDim.x) h[i] = 0;
    __syncthreads();
    int stride = gridDim.x * blockDim.x;
    for (int e = blockIdx.x * blockDim.x + threadIdx.x; e < NNZ; e += stride)
        atomicAdd(&h[rows[e] >> BSHIFT], 1);
    __syncthreads();
    for (int i = threadIdx.x; i < NBUCKETS; i += blockDim.x)
        if (h[i]) atomicAdd(&bucketcnt[i], h[i]);
}

__global__ void bucket_scan_kernel(const int* __restrict__ cnt,
                                   int* __restrict__ bucketoff,
                                   int* __restrict__ cursor) {
    __shared__ int sc[1024];
    int t = threadIdx.x;
    int i0 = t * 2, i1 = t * 2 + 1;
    int a = (i0 < NBUCKETS) ? cnt[i0] : 0;
    int b = (i1 < NBUCKETS) ? cnt[i1] : 0;
    sc[t] = a + b;
    __syncthreads();
    for (int o = 1; o < 1024; o <<= 1) {
        int v = (t >= o) ? sc[t - o] : 0;
        __syncthreads();
        sc[t] += v;
        __syncthreads();
    }
    int excl = (t == 0) ? 0 : sc[t - 1];
    if (i0 < NBUCKETS) { bucketoff[i0] = excl;     cursor[i0] = excl; }
    if (i1 < NBUCKETS) { bucketoff[i1] = excl + a; cursor[i1] = excl + a; }
    if (t == 0) bucketoff[NBUCKETS] = NNZ;
}

// Tile-aggregated scatter: one global atomic per touched bucket per block.
__global__ void bucket_scatter_kernel(const int* __restrict__ rows,
                                      const int* __restrict__ cols,
                                      const float* __restrict__ vals,
                                      int* __restrict__ cursor,
                                      int2* __restrict__ bucketed) {
    __shared__ int hist[NBUCKETS];
    __shared__ int lbase[NBUCKETS];
    int t = threadIdx.x;
    size_t start = (size_t)blockIdx.x * TILE;
    int n = (int)(((size_t)NNZ - start < TILE) ? ((size_t)NNZ - start) : TILE);

    for (int i = t; i < NBUCKETS; i += 256) hist[i] = 0;
    __syncthreads();
    for (int i = t; i < n; i += 256)
        atomicAdd(&hist[rows[start + i] >> BSHIFT], 1);
    __syncthreads();
    for (int i = t; i < NBUCKETS; i += 256) {
        int c = hist[i];
        lbase[i] = c ? atomicAdd(&cursor[i], c) : 0;
        hist[i] = 0;  // reuse as local rank counter
    }
    __syncthreads();
    for (int i = t; i < n; i += 256) {
        int r = rows[start + i];
        int bkt = r >> BSHIFT;
        int p = lbase[bkt] + atomicAdd(&hist[bkt], 1);
        bucketed[p] = make_int2(((r & (RPB - 1)) << 18) | cols[start + i],
                                __float_as_int(vals[start + i]));
    }
}

// Per-bucket counting sort in LDS -> exact CSR segment + row_start.
// Output edge format: x = col byte offset (col*128), y = f32 val bits.
__global__ void local_sort_kernel(const int* __restrict__ bucketoff,
                                  const int2* __restrict__ bucketed,
                                  int* __restrict__ row_start,
                                  int2* __restrict__ edges) {
    __shared__ int hist[RPB];
    __shared__ int sc[RPB];
    __shared__ int lcur[RPB];
    __shared__ int2 buf[BCAP];
    int b = blockIdx.x;
    int t = threadIdx.x;
    int s = bucketoff[b], e = bucketoff[b + 1], n = e - s;

    if (t < RPB) hist[t] = 0;
    __syncthreads();
    for (int i = t; i < n; i += 256) {
        int2 ev = bucketed[s + i];
        atomicAdd(&hist[(unsigned)ev.x >> 18], 1);
    }
    __syncthreads();
    if (t < RPB) sc[t] = hist[t];
    __syncthreads();
    for (int o = 1; o < RPB; o <<= 1) {
        int v = (t < RPB && t >= o) ? sc[t - o] : 0;
        __syncthreads();
        if (t < RPB) sc[t] += v;
        __syncthreads();
    }
    if (t < RPB) {
        int excl = (t == 0) ? 0 : sc[t - 1];
        lcur[t] = excl;
        int gr = b * RPB + t;
        if (gr < N_TOTAL) row_start[gr] = s + excl;
    }
    if (b == 0 && t == 0) row_start[N_TOTAL] = NNZ;
    __syncthreads();
    for (int i = t; i < n; i += 256) {
        int2 ev = bucketed[s + i];
        int rl = (unsigned)ev.x >> 18;
        int c  = ev.x & 0x3FFFF;
        int p = atomicAdd(&lcur[rl], 1);
        int2 outv = make_int2(c << 7, ev.y);   // pre-scaled byte offset
        if (p < BCAP) buf[p] = outv;
        else          edges[s + p] = outv;
    }
    __syncthreads();
    int m = (n < BCAP) ? n : BCAP;
    for (int i = t; i < m; i += 256) edges[s + i] = buf[i];
}

// ---------------- bf16 CSR SpMM, quarter-split ----------------
// One wave per row. quad = lane>>4 processes edges 4t+quad; ui = lane&15
// covers dims 4ui..4ui+3 via one uint2 load (16 lanes x 8 B = 128 B/edge).
__global__ void spmm_csr_kernel(const int* __restrict__ row_start,
                                const int2* __restrict__ edges,   // x = col*128
                                const char* __restrict__ emb_in,  // bf16 rows, 128 B
                                uint2* __restrict__ emb_out) {
    int wave = (blockIdx.x * blockDim.x + threadIdx.x) >> 6;
    int lane = threadIdx.x & 63;
    if (wave >= N_TOTAL) return;
    int quad = lane >> 4;
    int ui   = lane & 15;
    int s = row_start[wave];
    int e = row_start[wave + 1];
    float a0 = 0.f, a1 = 0.f, a2 = 0.f, a3 = 0.f;
    for (int base = s; base < e; base += 64) {
        int n = e - base; if (n > 64) n = 64;
        int c = 0; float v = 0.0f;
        if (base + lane < e) {
            int2 ev = edges[base + lane];
            c = ev.x; v = __int_as_float(ev.y);
        }
        int tmax = (n + 3) >> 2;
        for (int t = 0; t < tmax; ++t) {
            int j = 4 * t + quad;                  // < 64 always
            int   cj = __shfl(c, j, 64);
            float vj = __shfl(v, j, 64);
            float m  = (j < n) ? vj : 0.0f;
            uint2 p = *(const uint2*)(emb_in + cj + 8 * ui);
            a0 += m * bf16_lo(p.x);
            a1 += m * bf16_hi(p.x);
            a2 += m * bf16_lo(p.y);
            a3 += m * bf16_hi(p.y);
        }
    }
    a0 += __shfl_xor(a0, 16, 64); a1 += __shfl_xor(a1, 16, 64);
    a2 += __shfl_xor(a2, 16, 64); a3 += __shfl_xor(a3, 16, 64);
    a0 += __shfl_xor(a0, 32, 64); a1 += __shfl_xor(a1, 32, 64);
    a2 += __shfl_xor(a2, 32, 64); a3 += __shfl_xor(a3, 32, 64);
    if (quad == 0)
        emb_out[(size_t)wave * 16 + ui] = make_uint2(pack_bf16(a0, a1),
                                                     pack_bf16(a2, a3));
}

// Layer-3: segment sums ONLY for the 8192 batch rows, added into fp32 accs.
__global__ void layer3_kernel(const int* __restrict__ users,
                              const int* __restrict__ items,
                              const int* __restrict__ row_start,
                              const int2* __restrict__ edges,
                              const char* __restrict__ emb_in,  // bf16 rows
                              float* __restrict__ u_acc,
                              float* __restrict__ i_acc) {
    int wave = (blockIdx.x * blockDim.x + threadIdx.x) >> 6;
    int lane = threadIdx.x & 63;
    if (wave >= 2 * BATCH) return;
    int quad = lane >> 4;
    int ui   = lane & 15;
    int row;
    float* dst;
    if (wave < BATCH) {
        row = users[wave];
        dst = &u_acc[(size_t)wave * D];
    } else {
        int bb = wave - BATCH;
        row = N_USERS + items[bb];
        dst = &i_acc[(size_t)bb * D];
    }
    int s = row_start[row];
    int e = row_start[row + 1];
    float a0 = 0.f, a1 = 0.f, a2 = 0.f, a3 = 0.f;
    for (int base = s; base < e; base += 64) {
        int n = e - base; if (n > 64) n = 64;
        int c = 0; float v = 0.0f;
        if (base + lane < e) {
            int2 ev = edges[base + lane];
            c = ev.x; v = __int_as_float(ev.y);
        }
        int tmax = (n + 3) >> 2;
        for (int t = 0; t < tmax; ++t) {
            int j = 4 * t + quad;
            int   cj = __shfl(c, j, 64);
            float vj = __shfl(v, j, 64);
            float m  = (j < n) ? vj : 0.0f;
            uint2 p = *(const uint2*)(emb_in + cj + 8 * ui);
            a0 += m * bf16_lo(p.x);
            a1 += m * bf16_hi(p.x);
            a2 += m * bf16_lo(p.y);
            a3 += m * bf16_hi(p.y);
        }
    }
    a0 += __shfl_xor(a0, 16, 64); a1 += __shfl_xor(a1, 16, 64);
    a2 += __shfl_xor(a2, 16, 64); a3 += __shfl_xor(a3, 16, 64);
    a0 += __shfl_xor(a0, 32, 64); a1 += __shfl_xor(a1, 32, 64);
    a2 += __shfl_xor(a2, 32, 64); a3 += __shfl_xor(a3, 32, 64);
    if (quad == 0) {
        dst[4 * ui + 0] += a0;
        dst[4 * ui + 1] += a1;
        dst[4 * ui + 2] += a2;
        dst[4 * ui + 3] += a3;
    }
}

// After layers 1,2: pull bf16 emb rows at batch indices into fp32 accs.
__global__ void gather_acc_kernel(const int* __restrict__ users,
                                  const int* __restrict__ items,
                                  const unsigned* __restrict__ emb,  // bf16x2
                                  float* __restrict__ u_acc,
                                  float* __restrict__ i_acc) {
    int gid = blockIdx.x * blockDim.x + threadIdx.x;  // 2*BATCH*32 threads
    int ui = gid & 31;
    int b  = gid >> 5;
    if (b < BATCH) {
        unsigned p = emb[(size_t)users[b] * 32 + ui];
        u_acc[(size_t)b * D + 2 * ui]     += bf16_lo(p);
        u_acc[(size_t)b * D + 2 * ui + 1] += bf16_hi(p);
    } else if (b < 2 * BATCH) {
        int bb = b - BATCH;
        unsigned p = emb[((size_t)(N_USERS + items[bb])) * 32 + ui];
        i_acc[(size_t)bb * D + 2 * ui]     += bf16_lo(p);
        i_acc[(size_t)bb * D + 2 * ui + 1] += bf16_hi(p);
    }
}

__global__ void final_dot_kernel(const float* __restrict__ u_acc,
                                 const float* __restrict__ i_acc,
                                 float* __restrict__ out) {
    int gid = blockIdx.x * blockDim.x + threadIdx.x;
    int b = gid >> 6;
    int lane = gid & 63;
    if (b >= BATCH) return;
    float p = u_acc[(size_t)b * D + lane] * i_acc[(size_t)b * D + lane];
#pragma unroll
    for (int o = 32; o; o >>= 1) p += __shfl_xor(p, o, 64);
    if (lane == 0) out[b] = p * (1.0f / 16.0f);
}

// ---------------- launch ----------------

extern "C" void kernel_launch(void* const* d_in, const int* in_sizes, int n_in,
                              void* d_out, int out_size, void* d_ws, size_t ws_size,
                              hipStream_t stream) {
    const int*   users = (const int*)d_in[0];
    const int*   items = (const int*)d_in[1];
    const float* ue    = (const float*)d_in[2];
    const float* ie    = (const float*)d_in[3];
    const int*   rows  = (const int*)d_in[4];
    const int*   cols  = (const int*)d_in[5];
    const float* vals  = (const float*)d_in[6];
    float*       out   = (float*)d_out;

    char* ws = (char*)d_ws;
    size_t off = 0;
    auto alloc = [&](size_t bytes) {
        void* p = ws + off;
        off += (bytes + 255) & ~(size_t)255;
        return p;
    };
    const size_t NBH = (size_t)N_TOTAL * D * sizeof(unsigned short);  // 19.2 MB bf16
    char*  embA      = (char*)alloc(NBH);
    char*  embB      = (char*)alloc(NBH);
    float* u_acc     = (float*)alloc((size_t)BATCH * D * sizeof(float));
    float* i_acc     = (float*)alloc((size_t)BATCH * D * sizeof(float));
    int*   row_start = (int*)alloc(((size_t)N_TOTAL + 1) * sizeof(int));
    int*   bucketcnt = (int*)alloc((size_t)NBUCKETS * sizeof(int));
    int*   bucketoff = (int*)alloc(((size_t)NBUCKETS + 1) * sizeof(int));
    int*   cursor    = (int*)alloc((size_t)NBUCKETS * sizeof(int));
    int2*  edges     = (int2*)alloc((size_t)NNZ * sizeof(int2));
    int2*  bucketed  = (int2*)alloc((size_t)NNZ * sizeof(int2));

    // init
    {
        size_t tot4 = (size_t)N_TOTAL * D / 4;
        init_emb_kernel<<<(unsigned)((tot4 + 255) / 256), 256, 0, stream>>>(
            (const float4*)ue, (const float4*)ie, (uint2*)embA);
        init_acc_kernel<<<(2 * BATCH * D + 255) / 256, 256, 0, stream>>>(
            users, items, ue, ie, u_acc, i_acc);
    }

    // CSR build (two-level bucketing, tile-aggregated scatter)
    hipMemsetAsync(bucketcnt, 0, (size_t)NBUCKETS * sizeof(int), stream);
    bucket_hist_kernel<<<512, 256, 0, stream>>>(rows, bucketcnt);
    bucket_scan_kernel<<<1, 1024, 0, stream>>>(bucketcnt, bucketoff, cursor);
    bucket_scatter_kernel<<<SCAT_BLOCKS, 256, 0, stream>>>(
        rows, cols, vals, cursor, bucketed);
    local_sort_kernel<<<NBUCKETS, 256, 0, stream>>>(
        bucketoff, bucketed, row_start, edges);

    // Layer 1: embA -> embB
    spmm_csr_kernel<<<(N_TOTAL * 64 + 255) / 256, 256, 0, stream>>>(
        row_start, edges, embA, (uint2*)embB);
    gather_acc_kernel<<<(2 * BATCH * 32 + 255) / 256, 256, 0, stream>>>(
        users, items, (const unsigned*)embB, u_acc, i_acc);

    // Layer 2: embB -> embA
    spmm_csr_kernel<<<(N_TOTAL * 64 + 255) / 256, 256, 0, stream>>>(
        row_start, edges, embB, (uint2*)embA);
    gather_acc_kernel<<<(2 * BATCH * 32 + 255) / 256, 256, 0, stream>>>(
        users, items, (const unsigned*)embA, u_acc, i_acc);

    // Layer 3: only the 8192 batch rows, straight into accs
    layer3_kernel<<<(2 * BATCH * 64 + 255) / 256, 256, 0, stream>>>(
        users, items, row_start, edges, embA, u_acc, i_acc);

    final_dot_kernel<<<(BATCH * 64 + 255) / 256, 256, 0, stream>>>(u_acc, i_acc, out);
}

// Round 8
// 455.600 us; speedup vs baseline: 3.0195x; 1.0818x over previous
//
#include <hip/hip_runtime.h>

#define N_USERS 100000
#define M_ITEMS 50000
#define N_TOTAL (N_USERS + M_ITEMS)
#define D 64
#define NNZ 4000000
#define BATCH 4096

#define RPB 128                                   // rows per bucket (pow2)
#define BSHIFT 7
#define NBUCKETS ((N_TOTAL + RPB - 1) / RPB)      // 1172
#define BCAP 7680                                 // LDS edge capacity per bucket

#define TILE 16384                                // edges per scatter block
#define SCAT_BLOCKS ((NNZ + TILE - 1) / TILE)     // 245
#define SCAT_THREADS 1024
#define EPT (TILE / SCAT_THREADS)                 // 16 edges per thread

// ---- bf16 helpers (RNE) ----
__device__ __forceinline__ unsigned pack_bf16(float a, float b) {
    unsigned ua = __float_as_uint(a);
    unsigned ub = __float_as_uint(b);
    ua = (ua + 0x7FFFu + ((ua >> 16) & 1u)) >> 16;
    ub = (ub + 0x7FFFu + ((ub >> 16) & 1u)) & 0xFFFF0000u;
    return ua | ub;
}
__device__ __forceinline__ float bf16_lo(unsigned p) { return __uint_as_float(p << 16); }
__device__ __forceinline__ float bf16_hi(unsigned p) { return __uint_as_float(p & 0xFFFF0000u); }

// ---------------- init ----------------

// Concatenate + convert fp32 embeddings to packed bf16 (2 dims per uint).
__global__ void init_emb_kernel(const float4* __restrict__ ue,
                                const float4* __restrict__ ie,
                                uint2* __restrict__ emb) {
    size_t i = (size_t)blockIdx.x * blockDim.x + threadIdx.x;  // one float4 -> uint2
    const size_t nu4  = (size_t)N_USERS * D / 4;
    const size_t tot4 = (size_t)N_TOTAL * D / 4;
    if (i >= tot4) return;
    float4 f = (i < nu4) ? ue[i] : ie[i - nu4];
    emb[i] = make_uint2(pack_bf16(f.x, f.y), pack_bf16(f.z, f.w));
}

__global__ void init_acc_kernel(const int* __restrict__ users,
                                const int* __restrict__ items,
                                const float* __restrict__ ue,
                                const float* __restrict__ ie,
                                float* __restrict__ u_acc,
                                float* __restrict__ i_acc) {
    int gid = blockIdx.x * blockDim.x + threadIdx.x;  // 2*BATCH*D threads
    int d = gid & (D - 1);
    int b = gid >> 6;
    if (b < BATCH) {
        u_acc[(size_t)b * D + d] = ue[(size_t)users[b] * D + d];
    } else if (b < 2 * BATCH) {
        int bb = b - BATCH;
        i_acc[(size_t)bb * D + d] = ie[(size_t)items[bb] * D + d];
    }
}

// ---------------- CSR build: two-level bucketing ----------------

__global__ void bucket_hist_kernel(const int* __restrict__ rows,
                                   int* __restrict__ bucketcnt) {
    __shared__ int h[NBUCKETS];
    for (int i = threadIdx.x; i < NBUCKETS; i += blockDim.x) h[i] = 0;
    __syncthreads();
    int stride = gridDim.x * blockDim.x;
    for (int e = blockIdx.x * blockDim.x + threadIdx.x; e < NNZ; e += stride)
        atomicAdd(&h[rows[e] >> BSHIFT], 1);
    __syncthreads();
    for (int i = threadIdx.x; i < NBUCKETS; i += blockDim.x)
        if (h[i]) atomicAdd(&bucketcnt[i], h[i]);
}

__global__ void bucket_scan_kernel(const int* __restrict__ cnt,
                                   int* __restrict__ bucketoff,
                                   int* __restrict__ cursor) {
    __shared__ int sc[1024];
    int t = threadIdx.x;
    int i0 = t * 2, i1 = t * 2 + 1;
    int a = (i0 < NBUCKETS) ? cnt[i0] : 0;
    int b = (i1 < NBUCKETS) ? cnt[i1] : 0;
    sc[t] = a + b;
    __syncthreads();
    for (int o = 1; o < 1024; o <<= 1) {
        int v = (t >= o) ? sc[t - o] : 0;
        __syncthreads();
        sc[t] += v;
        __syncthreads();
    }
    int excl = (t == 0) ? 0 : sc[t - 1];
    if (i0 < NBUCKETS) { bucketoff[i0] = excl;     cursor[i0] = excl; }
    if (i1 < NBUCKETS) { bucketoff[i1] = excl + a; cursor[i1] = excl + a; }
    if (t == 0) bucketoff[NBUCKETS] = NNZ;
}

// Tile-aggregated scatter: one global atomic per touched bucket per block.
// 1024 threads (16 waves) for latency hiding; rank fused into phase-A hist.
__global__ __launch_bounds__(SCAT_THREADS)
void bucket_scatter_kernel(const int* __restrict__ rows,
                           const int* __restrict__ cols,
                           const float* __restrict__ vals,
                           int* __restrict__ cursor,
                           int2* __restrict__ bucketed) {
    __shared__ int hist[NBUCKETS];
    __shared__ int lbase[NBUCKETS];
    int t = threadIdx.x;
    size_t start = (size_t)blockIdx.x * TILE;
    int n = (int)(((size_t)NNZ - start < TILE) ? ((size_t)NNZ - start) : TILE);

    for (int i = t; i < NBUCKETS; i += SCAT_THREADS) hist[i] = 0;
    __syncthreads();
    // Phase A: histogram; atomicAdd's return value IS the local rank.
    int rank[EPT];
    int bkts[EPT];
#pragma unroll
    for (int k = 0; k < EPT; ++k) {
        int i = t + k * SCAT_THREADS;
        if (i < n) {
            int bkt = rows[start + i] >> BSHIFT;
            bkts[k] = bkt;
            rank[k] = atomicAdd(&hist[bkt], 1);
        }
    }
    __syncthreads();
    // Phase B: one global reservation per touched bucket
    for (int i = t; i < NBUCKETS; i += SCAT_THREADS) {
        int c = hist[i];
        lbase[i] = c ? atomicAdd(&cursor[i], c) : 0;
    }
    __syncthreads();
    // Phase C: write at reserved base + saved rank (no second LDS atomic pass)
#pragma unroll
    for (int k = 0; k < EPT; ++k) {
        int i = t + k * SCAT_THREADS;
        if (i < n) {
            int r = rows[start + i];
            int p = lbase[bkts[k]] + rank[k];
            bucketed[p] = make_int2(((r & (RPB - 1)) << 18) | cols[start + i],
                                    __float_as_int(vals[start + i]));
        }
    }
}

// Per-bucket counting sort in LDS -> exact CSR segment + row_start.
// Output edge format: x = col byte offset (col*128), y = f32 val bits.
__global__ void local_sort_kernel(const int* __restrict__ bucketoff,
                                  const int2* __restrict__ bucketed,
                                  int* __restrict__ row_start,
                                  int2* __restrict__ edges) {
    __shared__ int hist[RPB];
    __shared__ int sc[RPB];
    __shared__ int lcur[RPB];
    __shared__ int2 buf[BCAP];
    int b = blockIdx.x;
    int t = threadIdx.x;
    int s = bucketoff[b], e = bucketoff[b + 1], n = e - s;

    if (t < RPB) hist[t] = 0;
    __syncthreads();
    for (int i = t; i < n; i += 256) {
        int2 ev = bucketed[s + i];
        atomicAdd(&hist[(unsigned)ev.x >> 18], 1);
    }
    __syncthreads();
    if (t < RPB) sc[t] = hist[t];
    __syncthreads();
    for (int o = 1; o < RPB; o <<= 1) {
        int v = (t < RPB && t >= o) ? sc[t - o] : 0;
        __syncthreads();
        if (t < RPB) sc[t] += v;
        __syncthreads();
    }
    if (t < RPB) {
        int excl = (t == 0) ? 0 : sc[t - 1];
        lcur[t] = excl;
        int gr = b * RPB + t;
        if (gr < N_TOTAL) row_start[gr] = s + excl;
    }
    if (b == 0 && t == 0) row_start[N_TOTAL] = NNZ;
    __syncthreads();
    for (int i = t; i < n; i += 256) {
        int2 ev = bucketed[s + i];
        int rl = (unsigned)ev.x >> 18;
        int c  = ev.x & 0x3FFFF;
        int p = atomicAdd(&lcur[rl], 1);
        int2 outv = make_int2(c << 7, ev.y);   // pre-scaled byte offset
        if (p < BCAP) buf[p] = outv;
        else          edges[s + p] = outv;
    }
    __syncthreads();
    int m = (n < BCAP) ? n : BCAP;
    for (int i = t; i < m; i += 256) edges[s + i] = buf[i];
}

// ---------------- bf16 CSR SpMM, quarter-split ----------------
// One wave per row. quad = lane>>4 processes edges 4t+quad; ui = lane&15
// covers dims 4ui..4ui+3 via one uint2 load (16 lanes x 8 B = 128 B/edge).
__global__ void spmm_csr_kernel(const int* __restrict__ row_start,
                                const int2* __restrict__ edges,   // x = col*128
                                const char* __restrict__ emb_in,  // bf16 rows, 128 B
                                uint2* __restrict__ emb_out) {
    int wave = (blockIdx.x * blockDim.x + threadIdx.x) >> 6;
    int lane = threadIdx.x & 63;
    if (wave >= N_TOTAL) return;
    int quad = lane >> 4;
    int ui   = lane & 15;
    int s = row_start[wave];
    int e = row_start[wave + 1];
    float a0 = 0.f, a1 = 0.f, a2 = 0.f, a3 = 0.f;
    for (int base = s; base < e; base += 64) {
        int n = e - base; if (n > 64) n = 64;
        int c = 0; float v = 0.0f;
        if (base + lane < e) {
            int2 ev = edges[base + lane];
            c = ev.x; v = __int_as_float(ev.y);
        }
        int tmax = (n + 3) >> 2;
        for (int t = 0; t < tmax; ++t) {
            int j = 4 * t + quad;                  // < 64 always
            int   cj = __shfl(c, j, 64);
            float vj = __shfl(v, j, 64);
            float m  = (j < n) ? vj : 0.0f;
            uint2 p = *(const uint2*)(emb_in + cj + 8 * ui);
            a0 += m * bf16_lo(p.x);
            a1 += m * bf16_hi(p.x);
            a2 += m * bf16_lo(p.y);
            a3 += m * bf16_hi(p.y);
        }
    }
    a0 += __shfl_xor(a0, 16, 64); a1 += __shfl_xor(a1, 16, 64);
    a2 += __shfl_xor(a2, 16, 64); a3 += __shfl_xor(a3, 16, 64);
    a0 += __shfl_xor(a0, 32, 64); a1 += __shfl_xor(a1, 32, 64);
    a2 += __shfl_xor(a2, 32, 64); a3 += __shfl_xor(a3, 32, 64);
    if (quad == 0)
        emb_out[(size_t)wave * 16 + ui] = make_uint2(pack_bf16(a0, a1),
                                                     pack_bf16(a2, a3));
}

// Layer-3: segment sums ONLY for the 8192 batch rows, added into fp32 accs.
__global__ void layer3_kernel(const int* __restrict__ users,
                              const int* __restrict__ items,
                              const int* __restrict__ row_start,
                              const int2* __restrict__ edges,
                              const char* __restrict__ emb_in,  // bf16 rows
                              float* __restrict__ u_acc,
                              float* __restrict__ i_acc) {
    int wave = (blockIdx.x * blockDim.x + threadIdx.x) >> 6;
    int lane = threadIdx.x & 63;
    if (wave >= 2 * BATCH) return;
    int quad = lane >> 4;
    int ui   = lane & 15;
    int row;
    float* dst;
    if (wave < BATCH) {
        row = users[wave];
        dst = &u_acc[(size_t)wave * D];
    } else {
        int bb = wave - BATCH;
        row = N_USERS + items[bb];
        dst = &i_acc[(size_t)bb * D];
    }
    int s = row_start[row];
    int e = row_start[row + 1];
    float a0 = 0.f, a1 = 0.f, a2 = 0.f, a3 = 0.f;
    for (int base = s; base < e; base += 64) {
        int n = e - base; if (n > 64) n = 64;
        int c = 0; float v = 0.0f;
        if (base + lane < e) {
            int2 ev = edges[base + lane];
            c = ev.x; v = __int_as_float(ev.y);
        }
        int tmax = (n + 3) >> 2;
        for (int t = 0; t < tmax; ++t) {
            int j = 4 * t + quad;
            int   cj = __shfl(c, j, 64);
            float vj = __shfl(v, j, 64);
            float m  = (j < n) ? vj : 0.0f;
            uint2 p = *(const uint2*)(emb_in + cj + 8 * ui);
            a0 += m * bf16_lo(p.x);
            a1 += m * bf16_hi(p.x);
            a2 += m * bf16_lo(p.y);
            a3 += m * bf16_hi(p.y);
        }
    }
    a0 += __shfl_xor(a0, 16, 64); a1 += __shfl_xor(a1, 16, 64);
    a2 += __shfl_xor(a2, 16, 64); a3 += __shfl_xor(a3, 16, 64);
    a0 += __shfl_xor(a0, 32, 64); a1 += __shfl_xor(a1, 32, 64);
    a2 += __shfl_xor(a2, 32, 64); a3 += __shfl_xor(a3, 32, 64);
    if (quad == 0) {
        dst[4 * ui + 0] += a0;
        dst[4 * ui + 1] += a1;
        dst[4 * ui + 2] += a2;
        dst[4 * ui + 3] += a3;
    }
}

// After layers 1,2: pull bf16 emb rows at batch indices into fp32 accs.
__global__ void gather_acc_kernel(const int* __restrict__ users,
                                  const int* __restrict__ items,
                                  const unsigned* __restrict__ emb,  // bf16x2
                                  float* __restrict__ u_acc,
                                  float* __restrict__ i_acc) {
    int gid = blockIdx.x * blockDim.x + threadIdx.x;  // 2*BATCH*32 threads
    int ui = gid & 31;
    int b  = gid >> 5;
    if (b < BATCH) {
        unsigned p = emb[(size_t)users[b] * 32 + ui];
        u_acc[(size_t)b * D + 2 * ui]     += bf16_lo(p);
        u_acc[(size_t)b * D + 2 * ui + 1] += bf16_hi(p);
    } else if (b < 2 * BATCH) {
        int bb = b - BATCH;
        unsigned p = emb[((size_t)(N_USERS + items[bb])) * 32 + ui];
        i_acc[(size_t)bb * D + 2 * ui]     += bf16_lo(p);
        i_acc[(size_t)bb * D + 2 * ui + 1] += bf16_hi(p);
    }
}

__global__ void final_dot_kernel(const float* __restrict__ u_acc,
                                 const float* __restrict__ i_acc,
                                 float* __restrict__ out) {
    int gid = blockIdx.x * blockDim.x + threadIdx.x;
    int b = gid >> 6;
    int lane = gid & 63;
    if (b >= BATCH) return;
    float p = u_acc[(size_t)b * D + lane] * i_acc[(size_t)b * D + lane];
#pragma unroll
    for (int o = 32; o; o >>= 1) p += __shfl_xor(p, o, 64);
    if (lane == 0) out[b] = p * (1.0f / 16.0f);
}

// ---------------- launch ----------------

extern "C" void kernel_launch(void* const* d_in, const int* in_sizes, int n_in,
                              void* d_out, int out_size, void* d_ws, size_t ws_size,
                              hipStream_t stream) {
    const int*   users = (const int*)d_in[0];
    const int*   items = (const int*)d_in[1];
    const float* ue    = (const float*)d_in[2];
    const float* ie    = (const float*)d_in[3];
    const int*   rows  = (const int*)d_in[4];
    const int*   cols  = (const int*)d_in[5];
    const float* vals  = (const float*)d_in[6];
    float*       out   = (float*)d_out;

    char* ws = (char*)d_ws;
    size_t off = 0;
    auto alloc = [&](size_t bytes) {
        void* p = ws + off;
        off += (bytes + 255) & ~(size_t)255;
        return p;
    };
    const size_t NBH = (size_t)N_TOTAL * D * sizeof(unsigned short);  // 19.2 MB bf16
    char*  embA      = (char*)alloc(NBH);
    char*  embB      = (char*)alloc(NBH);
    float* u_acc     = (float*)alloc((size_t)BATCH * D * sizeof(float));
    float* i_acc     = (float*)alloc((size_t)BATCH * D * sizeof(float));
    int*   row_start = (int*)alloc(((size_t)N_TOTAL + 1) * sizeof(int));
    int*   bucketcnt = (int*)alloc((size_t)NBUCKETS * sizeof(int));
    int*   bucketoff = (int*)alloc(((size_t)NBUCKETS + 1) * sizeof(int));
    int*   cursor    = (int*)alloc((size_t)NBUCKETS * sizeof(int));
    int2*  edges     = (int2*)alloc((size_t)NNZ * sizeof(int2));
    int2*  bucketed  = (int2*)alloc((size_t)NNZ * sizeof(int2));

    // init
    {
        size_t tot4 = (size_t)N_TOTAL * D / 4;
        init_emb_kernel<<<(unsigned)((tot4 + 255) / 256), 256, 0, stream>>>(
            (const float4*)ue, (const float4*)ie, (uint2*)embA);
        init_acc_kernel<<<(2 * BATCH * D + 255) / 256, 256, 0, stream>>>(
            users, items, ue, ie, u_acc, i_acc);
    }

    // CSR build (two-level bucketing, tile-aggregated scatter)
    hipMemsetAsync(bucketcnt, 0, (size_t)NBUCKETS * sizeof(int), stream);
    bucket_hist_kernel<<<512, 256, 0, stream>>>(rows, bucketcnt);
    bucket_scan_kernel<<<1, 1024, 0, stream>>>(bucketcnt, bucketoff, cursor);
    bucket_scatter_kernel<<<SCAT_BLOCKS, SCAT_THREADS, 0, stream>>>(
        rows, cols, vals, cursor, bucketed);
    local_sort_kernel<<<NBUCKETS, 256, 0, stream>>>(
        bucketoff, bucketed, row_start, edges);

    // Layer 1: embA -> embB
    spmm_csr_kernel<<<(N_TOTAL * 64 + 255) / 256, 256, 0, stream>>>(
        row_start, edges, embA, (uint2*)embB);
    gather_acc_kernel<<<(2 * BATCH * 32 + 255) / 256, 256, 0, stream>>>(
        users, items, (const unsigned*)embB, u_acc, i_acc);

    // Layer 2: embB -> embA
    spmm_csr_kernel<<<(N_TOTAL * 64 + 255) / 256, 256, 0, stream>>>(
        row_start, edges, embB, (uint2*)embA);
    gather_acc_kernel<<<(2 * BATCH * 32 + 255) / 256, 256, 0, stream>>>(
        users, items, (const unsigned*)embA, u_acc, i_acc);

    // Layer 3: only the 8192 batch rows, straight into accs
    layer3_kernel<<<(2 * BATCH * 64 + 255) / 256, 256, 0, stream>>>(
        users, items, row_start, edges, embA, u_acc, i_acc);

    final_dot_kernel<<<(BATCH * 64 + 255) / 256, 256, 0, stream>>>(u_acc, i_acc, out);
}

// Round 9
// 409.883 us; speedup vs baseline: 3.3563x; 1.1115x over previous
//
#include <hip/hip_runtime.h>

#define N_USERS 100000
#define M_ITEMS 50000
#define N_TOTAL (N_USERS + M_ITEMS)
#define D 64
#define NNZ 4000000
#define BATCH 4096

#define RPB 128                                   // rows per bucket (pow2)
#define BSHIFT 7
#define NBUCKETS ((N_TOTAL + RPB - 1) / RPB)      // 1172
#define BCAP 7680                                 // LDS edge capacity per bucket

#define TILE 8192                                 // edges per scatter block
#define SCAT_BLOCKS ((NNZ + TILE - 1) / TILE)     // 489
#define SCAT_THREADS 512
#define EPT (TILE / SCAT_THREADS)                 // 16 edges per thread
#define CPB 3                                     // buckets per thread in block scan (512*3>=1172)

#define LS_THREADS 512
#define LS_EPT 16                                 // covers n <= 8192 > BCAP

// ---- bf16 helpers (RNE) ----
__device__ __forceinline__ unsigned pack_bf16(float a, float b) {
    unsigned ua = __float_as_uint(a);
    unsigned ub = __float_as_uint(b);
    ua = (ua + 0x7FFFu + ((ua >> 16) & 1u)) >> 16;
    ub = (ub + 0x7FFFu + ((ub >> 16) & 1u)) & 0xFFFF0000u;
    return ua | ub;
}
__device__ __forceinline__ float bf16_lo(unsigned p) { return __uint_as_float(p << 16); }
__device__ __forceinline__ float bf16_hi(unsigned p) { return __uint_as_float(p & 0xFFFF0000u); }

// ---------------- init ----------------

__global__ void init_emb_kernel(const float4* __restrict__ ue,
                                const float4* __restrict__ ie,
                                uint2* __restrict__ emb) {
    size_t i = (size_t)blockIdx.x * blockDim.x + threadIdx.x;  // one float4 -> uint2
    const size_t nu4  = (size_t)N_USERS * D / 4;
    const size_t tot4 = (size_t)N_TOTAL * D / 4;
    if (i >= tot4) return;
    float4 f = (i < nu4) ? ue[i] : ie[i - nu4];
    emb[i] = make_uint2(pack_bf16(f.x, f.y), pack_bf16(f.z, f.w));
}

__global__ void init_acc_kernel(const int* __restrict__ users,
                                const int* __restrict__ items,
                                const float* __restrict__ ue,
                                const float* __restrict__ ie,
                                float* __restrict__ u_acc,
                                float* __restrict__ i_acc) {
    int gid = blockIdx.x * blockDim.x + threadIdx.x;  // 2*BATCH*D threads
    int d = gid & (D - 1);
    int b = gid >> 6;
    if (b < BATCH) {
        u_acc[(size_t)b * D + d] = ue[(size_t)users[b] * D + d];
    } else if (b < 2 * BATCH) {
        int bb = b - BATCH;
        i_acc[(size_t)bb * D + d] = ie[(size_t)items[bb] * D + d];
    }
}

// ---------------- CSR build: two-level bucketing ----------------

__global__ void bucket_hist_kernel(const int* __restrict__ rows,
                                   int* __restrict__ bucketcnt) {
    __shared__ int h[NBUCKETS];
    for (int i = threadIdx.x; i < NBUCKETS; i += blockDim.x) h[i] = 0;
    __syncthreads();
    int stride = gridDim.x * blockDim.x;
    for (int e = blockIdx.x * blockDim.x + threadIdx.x; e < NNZ; e += stride)
        atomicAdd(&h[rows[e] >> BSHIFT], 1);
    __syncthreads();
    for (int i = threadIdx.x; i < NBUCKETS; i += blockDim.x)
        if (h[i]) atomicAdd(&bucketcnt[i], h[i]);
}

__global__ void bucket_scan_kernel(const int* __restrict__ cnt,
                                   int* __restrict__ bucketoff,
                                   int* __restrict__ cursor) {
    __shared__ int sc[1024];
    int t = threadIdx.x;
    int i0 = t * 2, i1 = t * 2 + 1;
    int a = (i0 < NBUCKETS) ? cnt[i0] : 0;
    int b = (i1 < NBUCKETS) ? cnt[i1] : 0;
    sc[t] = a + b;
    __syncthreads();
    for (int o = 1; o < 1024; o <<= 1) {
        int v = (t >= o) ? sc[t - o] : 0;
        __syncthreads();
        sc[t] += v;
        __syncthreads();
    }
    int excl = (t == 0) ? 0 : sc[t - 1];
    if (i0 < NBUCKETS) { bucketoff[i0] = excl;     cursor[i0] = excl; }
    if (i1 < NBUCKETS) { bucketoff[i1] = excl + a; cursor[i1] = excl + a; }
    if (t == 0) bucketoff[NBUCKETS] = NNZ;
}

// Tile-aggregated scatter with LDS staging: rank via fused hist atomic,
// block scan -> local offsets, one global reservation per touched bucket,
// place edges bucket-sorted in LDS, then stream each bucket's run out
// contiguously (back-to-back stores per 64B line).
__global__ __launch_bounds__(SCAT_THREADS)
void bucket_scatter_kernel(const int* __restrict__ rows,
                           const int* __restrict__ cols,
                           const float* __restrict__ vals,
                           int* __restrict__ cursor,
                           int2* __restrict__ bucketed) {
    __shared__ int hist[NBUCKETS];        // counts, then reused as global base
    __shared__ int loff[NBUCKETS + 1];    // local exclusive prefix
    __shared__ int partial[SCAT_THREADS];
    __shared__ int2 buf[TILE];            // 64 KB
    int t = threadIdx.x;
    size_t start = (size_t)blockIdx.x * TILE;
    int n = (int)(((size_t)NNZ - start < TILE) ? ((size_t)NNZ - start) : TILE);

    for (int i = t; i < NBUCKETS; i += SCAT_THREADS) hist[i] = 0;
    __syncthreads();
    // Phase A: histogram; atomicAdd's return IS the local rank.
    int rowv[EPT];
    int rank[EPT];
#pragma unroll
    for (int k = 0; k < EPT; ++k) {
        int i = t + k * SCAT_THREADS;
        if (i < n) {
            int r = rows[start + i];
            rowv[k] = r;
            rank[k] = atomicAdd(&hist[r >> BSHIFT], 1);
        }
    }
    __syncthreads();
    // Phase B1: block scan hist -> loff (exclusive)
    {
        int base = t * CPB;
        int s = 0;
#pragma unroll
        for (int j = 0; j < CPB; ++j) {
            int idx = base + j;
            if (idx < NBUCKETS) s += hist[idx];
        }
        partial[t] = s;
        __syncthreads();
        for (int o = 1; o < SCAT_THREADS; o <<= 1) {
            int v = (t >= o) ? partial[t - o] : 0;
            __syncthreads();
            partial[t] += v;
            __syncthreads();
        }
        int excl = (t == 0) ? 0 : partial[t - 1];
#pragma unroll
        for (int j = 0; j < CPB; ++j) {
            int idx = base + j;
            if (idx < NBUCKETS) { loff[idx] = excl; excl += hist[idx]; }
        }
        if (t == 0) loff[NBUCKETS] = n;
    }
    __syncthreads();
    // Phase B2: one global reservation per touched bucket; hist becomes lbase.
    for (int i = t; i < NBUCKETS; i += SCAT_THREADS) {
        int c = loff[i + 1] - loff[i];
        hist[i] = c ? atomicAdd(&cursor[i], c) : 0;
    }
    __syncthreads();
    // Phase C: place edges bucket-sorted in LDS.
#pragma unroll
    for (int k = 0; k < EPT; ++k) {
        int i = t + k * SCAT_THREADS;
        if (i < n) {
            int r = rowv[k];
            buf[loff[r >> BSHIFT] + rank[k]] =
                make_int2(((r & (RPB - 1)) << 18) | cols[start + i],
                          __float_as_int(vals[start + i]));
        }
    }
    __syncthreads();
    // Phase D: stream each bucket's contiguous run to its reserved range.
    for (int b = t; b < NBUCKETS; b += SCAT_THREADS) {
        int lo = loff[b], hi = loff[b + 1];
        int gb = hist[b];
        for (int i = lo; i < hi; ++i)
            bucketed[gb + (i - lo)] = buf[i];
    }
}

// Per-bucket counting sort in LDS (rank fused into the histogram pass).
// Output edge format: x = col byte offset (col*128), y = f32 val bits.
__global__ __launch_bounds__(LS_THREADS)
void local_sort_kernel(const int* __restrict__ bucketoff,
                       const int2* __restrict__ bucketed,
                       int* __restrict__ row_start,
                       int2* __restrict__ edges) {
    __shared__ int hist[RPB];
    __shared__ int sc[RPB];
    __shared__ int2 buf[BCAP];
    int b = blockIdx.x;
    int t = threadIdx.x;
    int s = bucketoff[b], e = bucketoff[b + 1], n = e - s;

    if (t < RPB) hist[t] = 0;
    __syncthreads();
    int rank[LS_EPT];
    int rl[LS_EPT];
#pragma unroll
    for (int k = 0; k < LS_EPT; ++k) {
        int i = t + k * LS_THREADS;
        if (i < n) {
            int2 ev = bucketed[s + i];
            rl[k] = (int)((unsigned)ev.x >> 18);
            rank[k] = atomicAdd(&hist[rl[k]], 1);
        }
    }
    __syncthreads();
    if (t < RPB) sc[t] = hist[t];
    __syncthreads();
    for (int o = 1; o < RPB; o <<= 1) {
        int v = (t < RPB && t >= o) ? sc[t - o] : 0;
        __syncthreads();
        if (t < RPB) sc[t] += v;
        __syncthreads();
    }
    if (t < RPB) {
        int excl = (t == 0) ? 0 : sc[t - 1];
        int gr = b * RPB + t;
        if (gr < N_TOTAL) row_start[gr] = s + excl;
    }
    if (b == 0 && t == 0) row_start[N_TOTAL] = NNZ;
    __syncthreads();
#pragma unroll
    for (int k = 0; k < LS_EPT; ++k) {
        int i = t + k * LS_THREADS;
        if (i < n) {
            int2 ev = bucketed[s + i];     // re-read, L2-warm
            int r = rl[k];
            int excl = (r == 0) ? 0 : sc[r - 1];
            int p = excl + rank[k];
            int2 outv = make_int2((ev.x & 0x3FFFF) << 7, ev.y);  // pre-scaled byte offset
            if (p < BCAP) buf[p] = outv;
            else          edges[s + p] = outv;
        }
    }
    __syncthreads();
    int m = (n < BCAP) ? n : BCAP;
    for (int i = t; i < m; i += LS_THREADS) edges[s + i] = buf[i];
}

// ---------------- bf16 CSR SpMM, quarter-split ----------------
// One wave per row. quad = lane>>4 processes edges 4t+quad; ui = lane&15
// covers dims 4ui..4ui+3 via one uint2 load (16 lanes x 8 B = 128 B/edge).
__global__ void spmm_csr_kernel(const int* __restrict__ row_start,
                                const int2* __restrict__ edges,   // x = col*128
                                const char* __restrict__ emb_in,  // bf16 rows, 128 B
                                uint2* __restrict__ emb_out) {
    int wave = (blockIdx.x * blockDim.x + threadIdx.x) >> 6;
    int lane = threadIdx.x & 63;
    if (wave >= N_TOTAL) return;
    int quad = lane >> 4;
    int ui   = lane & 15;
    int s = row_start[wave];
    int e = row_start[wave + 1];
    float a0 = 0.f, a1 = 0.f, a2 = 0.f, a3 = 0.f;
    for (int base = s; base < e; base += 64) {
        int n = e - base; if (n > 64) n = 64;
        int c = 0; float v = 0.0f;
        if (base + lane < e) {
            int2 ev = edges[base + lane];
            c = ev.x; v = __int_as_float(ev.y);
        }
        int tmax = (n + 3) >> 2;
        for (int t = 0; t < tmax; ++t) {
            int j = 4 * t + quad;                  // < 64 always
            int   cj = __shfl(c, j, 64);
            float vj = __shfl(v, j, 64);
            float m  = (j < n) ? vj : 0.0f;
            uint2 p = *(const uint2*)(emb_in + cj + 8 * ui);
            a0 += m * bf16_lo(p.x);
            a1 += m * bf16_hi(p.x);
            a2 += m * bf16_lo(p.y);
            a3 += m * bf16_hi(p.y);
        }
    }
    a0 += __shfl_xor(a0, 16, 64); a1 += __shfl_xor(a1, 16, 64);
    a2 += __shfl_xor(a2, 16, 64); a3 += __shfl_xor(a3, 16, 64);
    a0 += __shfl_xor(a0, 32, 64); a1 += __shfl_xor(a1, 32, 64);
    a2 += __shfl_xor(a2, 32, 64); a3 += __shfl_xor(a3, 32, 64);
    if (quad == 0)
        emb_out[(size_t)wave * 16 + ui] = make_uint2(pack_bf16(a0, a1),
                                                     pack_bf16(a2, a3));
}

// Layer-3: segment sums ONLY for the 8192 batch rows, added into fp32 accs.
__global__ void layer3_kernel(const int* __restrict__ users,
                              const int* __restrict__ items,
                              const int* __restrict__ row_start,
                              const int2* __restrict__ edges,
                              const char* __restrict__ emb_in,  // bf16 rows
                              float* __restrict__ u_acc,
                              float* __restrict__ i_acc) {
    int wave = (blockIdx.x * blockDim.x + threadIdx.x) >> 6;
    int lane = threadIdx.x & 63;
    if (wave >= 2 * BATCH) return;
    int quad = lane >> 4;
    int ui   = lane & 15;
    int row;
    float* dst;
    if (wave < BATCH) {
        row = users[wave];
        dst = &u_acc[(size_t)wave * D];
    } else {
        int bb = wave - BATCH;
        row = N_USERS + items[bb];
        dst = &i_acc[(size_t)bb * D];
    }
    int s = row_start[row];
    int e = row_start[row + 1];
    float a0 = 0.f, a1 = 0.f, a2 = 0.f, a3 = 0.f;
    for (int base = s; base < e; base += 64) {
        int n = e - base; if (n > 64) n = 64;
        int c = 0; float v = 0.0f;
        if (base + lane < e) {
            int2 ev = edges[base + lane];
            c = ev.x; v = __int_as_float(ev.y);
        }
        int tmax = (n + 3) >> 2;
        for (int t = 0; t < tmax; ++t) {
            int j = 4 * t + quad;
            int   cj = __shfl(c, j, 64);
            float vj = __shfl(v, j, 64);
            float m  = (j < n) ? vj : 0.0f;
            uint2 p = *(const uint2*)(emb_in + cj + 8 * ui);
            a0 += m * bf16_lo(p.x);
            a1 += m * bf16_hi(p.x);
            a2 += m * bf16_lo(p.y);
            a3 += m * bf16_hi(p.y);
        }
    }
    a0 += __shfl_xor(a0, 16, 64); a1 += __shfl_xor(a1, 16, 64);
    a2 += __shfl_xor(a2, 16, 64); a3 += __shfl_xor(a3, 16, 64);
    a0 += __shfl_xor(a0, 32, 64); a1 += __shfl_xor(a1, 32, 64);
    a2 += __shfl_xor(a2, 32, 64); a3 += __shfl_xor(a3, 32, 64);
    if (quad == 0) {
        dst[4 * ui + 0] += a0;
        dst[4 * ui + 1] += a1;
        dst[4 * ui + 2] += a2;
        dst[4 * ui + 3] += a3;
    }
}

// After layers 1,2: pull bf16 emb rows at batch indices into fp32 accs.
__global__ void gather_acc_kernel(const int* __restrict__ users,
                                  const int* __restrict__ items,
                                  const unsigned* __restrict__ emb,  // bf16x2
                                  float* __restrict__ u_acc,
                                  float* __restrict__ i_acc) {
    int gid = blockIdx.x * blockDim.x + threadIdx.x;  // 2*BATCH*32 threads
    int ui = gid & 31;
    int b  = gid >> 5;
    if (b < BATCH) {
        unsigned p = emb[(size_t)users[b] * 32 + ui];
        u_acc[(size_t)b * D + 2 * ui]     += bf16_lo(p);
        u_acc[(size_t)b * D + 2 * ui + 1] += bf16_hi(p);
    } else if (b < 2 * BATCH) {
        int bb = b - BATCH;
        unsigned p = emb[((size_t)(N_USERS + items[bb])) * 32 + ui];
        i_acc[(size_t)bb * D + 2 * ui]     += bf16_lo(p);
        i_acc[(size_t)bb * D + 2 * ui + 1] += bf16_hi(p);
    }
}

__global__ void final_dot_kernel(const float* __restrict__ u_acc,
                                 const float* __restrict__ i_acc,
                                 float* __restrict__ out) {
    int gid = blockIdx.x * blockDim.x + threadIdx.x;
    int b = gid >> 6;
    int lane = gid & 63;
    if (b >= BATCH) return;
    float p = u_acc[(size_t)b * D + lane] * i_acc[(size_t)b * D + lane];
#pragma unroll
    for (int o = 32; o; o >>= 1) p += __shfl_xor(p, o, 64);
    if (lane == 0) out[b] = p * (1.0f / 16.0f);
}

// ---------------- launch ----------------

extern "C" void kernel_launch(void* const* d_in, const int* in_sizes, int n_in,
                              void* d_out, int out_size, void* d_ws, size_t ws_size,
                              hipStream_t stream) {
    const int*   users = (const int*)d_in[0];
    const int*   items = (const int*)d_in[1];
    const float* ue    = (const float*)d_in[2];
    const float* ie    = (const float*)d_in[3];
    const int*   rows  = (const int*)d_in[4];
    const int*   cols  = (const int*)d_in[5];
    const float* vals  = (const float*)d_in[6];
    float*       out   = (float*)d_out;

    char* ws = (char*)d_ws;
    size_t off = 0;
    auto alloc = [&](size_t bytes) {
        void* p = ws + off;
        off += (bytes + 255) & ~(size_t)255;
        return p;
    };
    const size_t NBH = (size_t)N_TOTAL * D * sizeof(unsigned short);  // 19.2 MB bf16
    char*  embA      = (char*)alloc(NBH);
    char*  embB      = (char*)alloc(NBH);
    float* u_acc     = (float*)alloc((size_t)BATCH * D * sizeof(float));
    float* i_acc     = (float*)alloc((size_t)BATCH * D * sizeof(float));
    int*   row_start = (int*)alloc(((size_t)N_TOTAL + 1) * sizeof(int));
    int*   bucketcnt = (int*)alloc((size_t)NBUCKETS * sizeof(int));
    int*   bucketoff = (int*)alloc(((size_t)NBUCKETS + 1) * sizeof(int));
    int*   cursor    = (int*)alloc((size_t)NBUCKETS * sizeof(int));
    int2*  edges     = (int2*)alloc((size_t)NNZ * sizeof(int2));
    int2*  bucketed  = (int2*)alloc((size_t)NNZ * sizeof(int2));

    // init
    {
        size_t tot4 = (size_t)N_TOTAL * D / 4;
        init_emb_kernel<<<(unsigned)((tot4 + 255) / 256), 256, 0, stream>>>(
            (const float4*)ue, (const float4*)ie, (uint2*)embA);
        init_acc_kernel<<<(2 * BATCH * D + 255) / 256, 256, 0, stream>>>(
            users, items, ue, ie, u_acc, i_acc);
    }

    // CSR build (two-level bucketing, LDS-staged tile-aggregated scatter)
    hipMemsetAsync(bucketcnt, 0, (size_t)NBUCKETS * sizeof(int), stream);
    bucket_hist_kernel<<<512, 256, 0, stream>>>(rows, bucketcnt);
    bucket_scan_kernel<<<1, 1024, 0, stream>>>(bucketcnt, bucketoff, cursor);
    bucket_scatter_kernel<<<SCAT_BLOCKS, SCAT_THREADS, 0, stream>>>(
        rows, cols, vals, cursor, bucketed);
    local_sort_kernel<<<NBUCKETS, LS_THREADS, 0, stream>>>(
        bucketoff, bucketed, row_start, edges);

    // Layer 1: embA -> embB
    spmm_csr_kernel<<<(N_TOTAL * 64 + 255) / 256, 256, 0, stream>>>(
        row_start, edges, embA, (uint2*)embB);
    gather_acc_kernel<<<(2 * BATCH * 32 + 255) / 256, 256, 0, stream>>>(
        users, items, (const unsigned*)embB, u_acc, i_acc);

    // Layer 2: embB -> embA
    spmm_csr_kernel<<<(N_TOTAL * 64 + 255) / 256, 256, 0, stream>>>(
        row_start, edges, embB, (uint2*)embA);
    gather_acc_kernel<<<(2 * BATCH * 32 + 255) / 256, 256, 0, stream>>>(
        users, items, (const unsigned*)embA, u_acc, i_acc);

    // Layer 3: only the 8192 batch rows, straight into accs
    layer3_kernel<<<(2 * BATCH * 64 + 255) / 256, 256, 0, stream>>>(
        users, items, row_start, edges, embA, u_acc, i_acc);

    final_dot_kernel<<<(BATCH * 64 + 255) / 256, 256, 0, stream>>>(u_acc, i_acc, out);
}